// Round 1
// baseline (598.435 us; speedup 1.0000x reference)
//
#include <hip/hip_runtime.h>
#include <math.h>

#define BSZ 32
#define NN 1000
#define NNODES (BSZ*NN)
#define D_IN 6
#define HID 64
#define NH 4
#define CH (NH*HID)   /* 256 */
#define OUTD 5
#define OBS_STRIDE (NN*8+1)  /* 8001 */

// ---------------- encoder: feats(6) -> relu(64) -> relu(64) ----------------
__global__ __launch_bounds__(256) void encoder_kernel(
    const float* __restrict__ obs,
    const float* __restrict__ w1, const float* __restrict__ b1,
    const float* __restrict__ w2, const float* __restrict__ b2,
    float* __restrict__ h_out)
{
    __shared__ float W1s[6*64];
    __shared__ float W2s[64*64];
    __shared__ float B1s[64], B2s[64];
    __shared__ float fs[4][6];
    __shared__ float h1s[4][64];

    int tid = threadIdx.x;
    for (int i = tid; i < 6*64; i += 256) W1s[i] = w1[i];
    for (int i = tid; i < 64*64; i += 256) W2s[i] = w2[i];
    if (tid < 64) { B1s[tid] = b1[tid]; B2s[tid] = b2[tid]; }

    int nl = tid >> 6, j = tid & 63;
    int n = blockIdx.x * 4 + nl;
    int b = n / NN, r = n % NN;
    if (j < 6) fs[nl][j] = obs[b*OBS_STRIDE + r*8 + 2 + j];
    __syncthreads();

    float acc = B1s[j];
    #pragma unroll
    for (int i = 0; i < 6; i++) acc += fs[nl][i] * W1s[i*64 + j];
    h1s[nl][j] = fmaxf(acc, 0.f);
    __syncthreads();

    float acc2 = B2s[j];
    #pragma unroll
    for (int i = 0; i < 64; i++) acc2 += h1s[nl][i] * W2s[i*64 + j];
    h_out[n*64 + j] = fmaxf(acc2, 0.f);
}

// ---------------- CSR build ----------------
__global__ void count_kernel(const int* __restrict__ dst, int E, int* __restrict__ counts)
{
    int e = blockIdx.x * 256 + threadIdx.x;
    if (e < E) atomicAdd(&counts[dst[e]], 1);
}

__global__ __launch_bounds__(1024) void scan_kernel(
    const int* __restrict__ counts, int* __restrict__ offs)
{
    __shared__ int ps[1024];
    int t = threadIdx.x;
    int base = t * 32;
    int s = 0;
    #pragma unroll 4
    for (int i = 0; i < 32; i++) { int idx = base + i; if (idx < NNODES) s += counts[idx]; }
    ps[t] = s;
    __syncthreads();
    for (int o = 1; o < 1024; o <<= 1) {
        int v = (t >= o) ? ps[t - o] : 0;
        __syncthreads();
        ps[t] += v;
        __syncthreads();
    }
    int off = ps[t] - s;   // exclusive
    for (int i = 0; i < 32; i++) {
        int idx = base + i;
        if (idx < NNODES) { offs[idx] = off; off += counts[idx]; }
    }
}

__global__ void scatter_kernel(const int* __restrict__ ei, int E,
                               const int* __restrict__ offs,
                               int* __restrict__ cursor, int* __restrict__ csr_src)
{
    int e = blockIdx.x * 256 + threadIdx.x;
    if (e < E) {
        int s = ei[e];
        int d = ei[E + e];
        int p = offs[d] + atomicAdd(&cursor[d], 1);
        csr_src[p] = s;
    }
}

// ---------------- QKV GEMM: C = X@W + b, X: 32000xK, W: KxCH ----------------
template<int K>
__global__ __launch_bounds__(256) void qkv_gemm(
    const float* __restrict__ X,
    const float* __restrict__ wq, const float* __restrict__ bq,
    const float* __restrict__ wk, const float* __restrict__ bk,
    const float* __restrict__ wv, const float* __restrict__ bv,
    float* __restrict__ Q, float* __restrict__ Ko, float* __restrict__ V)
{
    const float* W; const float* Bb; float* C;
    int z = blockIdx.z;
    if (z == 0)      { W = wq; Bb = bq; C = Q;  }
    else if (z == 1) { W = wk; Bb = bk; C = Ko; }
    else             { W = wv; Bb = bv; C = V;  }

    __shared__ float Xs[64][17];   // +1 pad: kills 4-way bank conflict on broadcast reads
    __shared__ float Ws[16][64];

    int tid = threadIdx.x;
    int tx = tid & 15, ty = tid >> 4;
    int bm = blockIdx.x * 64;
    int bn = blockIdx.y * 64;

    float acc[4][4] = {};
    int xr = tid >> 2, xc = (tid & 3) * 4;
    int wr = tid >> 4, wc = (tid & 15) * 4;

    for (int k0 = 0; k0 < K; k0 += 16) {
        float4 xv = *(const float4*)&X[(size_t)(bm + xr)*K + k0 + xc];
        Xs[xr][xc]   = xv.x; Xs[xr][xc+1] = xv.y;
        Xs[xr][xc+2] = xv.z; Xs[xr][xc+3] = xv.w;
        *(float4*)&Ws[wr][wc] = *(const float4*)&W[(size_t)(k0 + wr)*CH + bn + wc];
        __syncthreads();
        #pragma unroll
        for (int kk = 0; kk < 16; kk++) {
            float a[4], bb[4];
            #pragma unroll
            for (int i = 0; i < 4; i++) a[i] = Xs[ty*4 + i][kk];
            #pragma unroll
            for (int j = 0; j < 4; j++) bb[j] = Ws[kk][tx*4 + j];
            #pragma unroll
            for (int i = 0; i < 4; i++)
                #pragma unroll
                for (int j = 0; j < 4; j++) acc[i][j] += a[i] * bb[j];
        }
        __syncthreads();
    }

    #pragma unroll
    for (int i = 0; i < 4; i++) {
        int row = bm + ty*4 + i;
        float4 o;
        o.x = acc[i][0] + Bb[bn + tx*4 + 0];
        o.y = acc[i][1] + Bb[bn + tx*4 + 1];
        o.z = acc[i][2] + Bb[bn + tx*4 + 2];
        o.w = acc[i][3] + Bb[bn + tx*4 + 3];
        *(float4*)&C[(size_t)row*CH + bn + tx*4] = o;
    }
}

// ---------------- edge-softmax aggregation, one wave per node ----------------
// lane layout: head h = lane>>4, owns dims [h*64 + (lane&15)*4 .. +3] == lane*4..lane*4+3
__global__ __launch_bounds__(256) void attn_kernel(
    const float* __restrict__ Q, const float* __restrict__ Kf, const float* __restrict__ V,
    const int* __restrict__ offs, const int* __restrict__ counts,
    const int* __restrict__ csr_src, float* __restrict__ Xout)
{
    int tid = threadIdx.x;
    int wv = tid >> 6, lane = tid & 63;
    int n = blockIdx.x * 4 + wv;

    float4 qv = *(const float4*)&Q[(size_t)n*CH + lane*4];
    int start = offs[n], deg = counts[n];

    float m = -INFINITY, l = 0.f;
    float4 acc = {0.f, 0.f, 0.f, 0.f};

    for (int e = 0; e < deg; e++) {
        int src = csr_src[start + e];
        float4 kv = *(const float4*)&Kf[(size_t)src*CH + lane*4];
        float part = qv.x*kv.x + qv.y*kv.y + qv.z*kv.z + qv.w*kv.w;
        part += __shfl_xor(part, 8, 16);
        part += __shfl_xor(part, 4, 16);
        part += __shfl_xor(part, 2, 16);
        part += __shfl_xor(part, 1, 16);
        float s = part * 0.125f;       // / sqrt(64)
        float mn = fmaxf(m, s);
        float scale = __expf(m - mn);  // 0 when m == -inf
        float p = __expf(s - mn);
        l = l * scale + p;
        float4 vv = *(const float4*)&V[(size_t)src*CH + lane*4];
        acc.x = acc.x*scale + p*vv.x;
        acc.y = acc.y*scale + p*vv.y;
        acc.z = acc.z*scale + p*vv.z;
        acc.w = acc.w*scale + p*vv.w;
        m = mn;
    }
    float inv = (l > 0.f) ? 1.f / l : 0.f;
    float4 o;
    o.x = fmaxf(acc.x*inv, 0.f);
    o.y = fmaxf(acc.y*inv, 0.f);
    o.z = fmaxf(acc.z*inv, 0.f);
    o.w = fmaxf(acc.w*inv, 0.f);
    *(float4*)&Xout[(size_t)n*CH + lane*4] = o;
}

// ---------------- output head: gather agent rows, 256x5 linear ----------------
__global__ __launch_bounds__(64) void out_kernel(
    const float* __restrict__ obs, const float* __restrict__ X,
    const float* __restrict__ ow, const float* __restrict__ ob,
    float* __restrict__ out)
{
    int b = blockIdx.x, lane = threadIdx.x;
    float a = obs[b*OBS_STRIDE + NN*8];
    int agent = (int)fminf(fmaxf(a, 0.f), (float)(NN - 1));
    int g = b*NN + agent;

    float partial[OUTD] = {};
    #pragma unroll
    for (int c = 0; c < 4; c++) {
        int k = c*64 + lane;
        float xv = X[(size_t)g*CH + k];
        #pragma unroll
        for (int j = 0; j < OUTD; j++) partial[j] += xv * ow[k*OUTD + j];
    }
    #pragma unroll
    for (int j = 0; j < OUTD; j++) {
        #pragma unroll
        for (int o = 32; o >= 1; o >>= 1) partial[j] += __shfl_xor(partial[j], o, 64);
    }
    if (lane == 0) {
        #pragma unroll
        for (int j = 0; j < OUTD; j++) out[b*OUTD + j] = partial[j] + ob[j];
    }
}

extern "C" void kernel_launch(void* const* d_in, const int* in_sizes, int n_in,
                              void* d_out, int out_size, void* d_ws, size_t ws_size,
                              hipStream_t stream)
{
    const float* obs    = (const float*)d_in[0];
    const int*   ei     = (const int*)d_in[1];
    const int    E      = in_sizes[1] / 2;
    const float* enc_w1 = (const float*)d_in[2];
    const float* enc_b1 = (const float*)d_in[3];
    const float* enc_w2 = (const float*)d_in[4];
    const float* enc_b2 = (const float*)d_in[5];
    const float* c1_wq  = (const float*)d_in[6];
    const float* c1_bq  = (const float*)d_in[7];
    const float* c1_wk  = (const float*)d_in[8];
    const float* c1_bk  = (const float*)d_in[9];
    const float* c1_wv  = (const float*)d_in[10];
    const float* c1_bv  = (const float*)d_in[11];
    const float* c2_wq  = (const float*)d_in[12];
    const float* c2_bq  = (const float*)d_in[13];
    const float* c2_wk  = (const float*)d_in[14];
    const float* c2_bk  = (const float*)d_in[15];
    const float* c2_wv  = (const float*)d_in[16];
    const float* c2_bv  = (const float*)d_in[17];
    const float* out_w  = (const float*)d_in[18];
    const float* out_b  = (const float*)d_in[19];
    float* dout = (float*)d_out;

    float* ws    = (float*)d_ws;
    float* h_enc = ws;                         // 32000*64
    float* Qb    = h_enc + (size_t)NNODES*HID; // 32000*256
    float* Kb    = Qb + (size_t)NNODES*CH;
    float* Vb    = Kb + (size_t)NNODES*CH;
    float* X1    = Vb + (size_t)NNODES*CH;     // conv output (reused for conv2 out)
    int* counts  = (int*)(X1 + (size_t)NNODES*CH);
    int* offs    = counts + NNODES;
    int* cursor  = offs + NNODES;
    int* csr     = cursor + NNODES;            // E entries

    hipMemsetAsync(counts, 0, NNODES*sizeof(int), stream);
    hipMemsetAsync(cursor, 0, NNODES*sizeof(int), stream);

    int egrid = (E + 255) / 256;
    count_kernel<<<egrid, 256, 0, stream>>>(ei + E, E, counts);
    scan_kernel<<<1, 1024, 0, stream>>>(counts, offs);
    scatter_kernel<<<egrid, 256, 0, stream>>>(ei, E, offs, cursor, csr);

    encoder_kernel<<<NNODES/4, 256, 0, stream>>>(obs, enc_w1, enc_b1, enc_w2, enc_b2, h_enc);

    dim3 ggrid(NNODES/64, CH/64, 3);
    qkv_gemm<HID><<<ggrid, 256, 0, stream>>>(h_enc, c1_wq, c1_bq, c1_wk, c1_bk, c1_wv, c1_bv,
                                             Qb, Kb, Vb);
    attn_kernel<<<NNODES/4, 256, 0, stream>>>(Qb, Kb, Vb, offs, counts, csr, X1);

    qkv_gemm<CH><<<ggrid, 256, 0, stream>>>(X1, c2_wq, c2_bq, c2_wk, c2_bk, c2_wv, c2_bv,
                                            Qb, Kb, Vb);
    attn_kernel<<<NNODES/4, 256, 0, stream>>>(Qb, Kb, Vb, offs, counts, csr, X1);

    out_kernel<<<BSZ, 64, 0, stream>>>(obs, X1, out_w, out_b, dout);
}

// Round 7
// 483.402 us; speedup vs baseline: 1.2380x; 1.2380x over previous
//
#include <hip/hip_runtime.h>
#include <math.h>

#define BSZ 32
#define NN 1000
#define NNODES (BSZ*NN)
#define D_IN 6
#define HID 64
#define NH 4
#define CH (NH*HID)   /* 256 */
#define OUTD 5
#define OBS_STRIDE (NN*8+1)  /* 8001 */

// ---------------- encoder: feats(6) -> relu(64) -> relu(64), 16 nodes/block ----------------
__global__ __launch_bounds__(256) void encoder_kernel(
    const float* __restrict__ obs,
    const float* __restrict__ w1, const float* __restrict__ b1,
    const float* __restrict__ w2, const float* __restrict__ b2,
    float* __restrict__ h_out)
{
    __shared__ float W1s[6*64];
    __shared__ float W2s[64*64];
    __shared__ float B1s[64], B2s[64];
    __shared__ float fs[16][6];
    __shared__ float h1s[4][64];

    int tid = threadIdx.x;
    for (int i = tid; i < 6*64; i += 256) W1s[i] = w1[i];
    for (int i = tid; i < 64*64; i += 256) W2s[i] = w2[i];
    if (tid < 64) { B1s[tid] = b1[tid]; B2s[tid] = b2[tid]; }

    int n0 = blockIdx.x * 16;
    if (tid < 96) {
        int node = tid / 6, f = tid % 6;
        int n = n0 + node;
        fs[node][f] = obs[(n/NN)*OBS_STRIDE + (n%NN)*8 + 2 + f];
    }
    int nl = tid >> 6, j = tid & 63;
    __syncthreads();

    #pragma unroll
    for (int p = 0; p < 4; p++) {
        int ln = p*4 + nl;
        float acc = B1s[j];
        #pragma unroll
        for (int i = 0; i < 6; i++) acc += fs[ln][i] * W1s[i*64 + j];
        h1s[nl][j] = fmaxf(acc, 0.f);
        __syncthreads();
        float acc2 = B2s[j];
        #pragma unroll
        for (int i = 0; i < 64; i++) acc2 += h1s[nl][i] * W2s[i*64 + j];
        h_out[(size_t)(n0 + ln)*64 + j] = fmaxf(acc2, 0.f);
        __syncthreads();
    }
}

// ---------------- CSR build ----------------
__global__ void count_kernel(const int* __restrict__ dst, int E, int* __restrict__ counts)
{
    int e = blockIdx.x * 256 + threadIdx.x;
    if (e < E) atomicAdd(&counts[dst[e]], 1);
}

__global__ __launch_bounds__(1024) void scan_kernel(
    const int* __restrict__ counts, int* __restrict__ offs)
{
    __shared__ int ps[1024];
    int t = threadIdx.x;
    int base = t * 32;
    int s = 0;
    #pragma unroll 4
    for (int i = 0; i < 32; i++) { int idx = base + i; if (idx < NNODES) s += counts[idx]; }
    ps[t] = s;
    __syncthreads();
    for (int o = 1; o < 1024; o <<= 1) {
        int v = (t >= o) ? ps[t - o] : 0;
        __syncthreads();
        ps[t] += v;
        __syncthreads();
    }
    int off = ps[t] - s;   // exclusive
    for (int i = 0; i < 32; i++) {
        int idx = base + i;
        if (idx < NNODES) { offs[idx] = off; off += counts[idx]; }
    }
}

__global__ void scatter_kernel(const int* __restrict__ ei, int E,
                               const int* __restrict__ offs,
                               int* __restrict__ cursor, int* __restrict__ csr_src)
{
    int e = blockIdx.x * 256 + threadIdx.x;
    if (e < E) {
        int s = ei[e];
        int d = ei[E + e];
        int p = offs[d] + atomicAdd(&cursor[d], 1);
        csr_src[p] = s;
    }
}

// ---------------- QKV GEMM: 128x128 tile, 8x8/thread, transposed-X LDS ----------------
// z=0 -> Q (ld 256), z=1 -> K rows of KV (ld 512), z=2 -> V rows of KV (ld 512, +256)
template<int K>
__global__ __launch_bounds__(256) void qkv_gemm(
    const float* __restrict__ X,
    const float* __restrict__ wq, const float* __restrict__ bq,
    const float* __restrict__ wk, const float* __restrict__ bk,
    const float* __restrict__ wv, const float* __restrict__ bv,
    float* __restrict__ Q, float* __restrict__ KV)
{
    const float* W; const float* Bb; float* C; int ldc;
    int z = blockIdx.z;
    if (z == 0)      { W = wq; Bb = bq; C = Q;        ldc = CH;  }
    else if (z == 1) { W = wk; Bb = bk; C = KV;       ldc = 512; }
    else             { W = wv; Bb = bv; C = KV + 256; ldc = 512; }

    __shared__ float XsT[16][132];  // transposed X tile: [k][row], pad keeps b128 align + banks spread
    __shared__ float Ws[16][128];

    int tid = threadIdx.x;
    int bm = blockIdx.x * 128;
    int bn = blockIdx.y * 128;

    // staging indices
    int xr = tid >> 1, xk = (tid & 1) * 8;       // X: row, k-offset (8 floats)
    int wr = tid >> 4, wc = (tid & 15) * 8;      // W: k-row, col-offset (8 floats)
    // compute indices
    int rg = tid >> 4, cg = tid & 15;            // 8-row group, 8-col group

    float acc[8][8] = {};

    for (int k0 = 0; k0 < K; k0 += 16) {
        float4 xa = *(const float4*)&X[(size_t)(bm + xr)*K + k0 + xk];
        float4 xb = *(const float4*)&X[(size_t)(bm + xr)*K + k0 + xk + 4];
        float4 wa = *(const float4*)&W[(size_t)(k0 + wr)*CH + bn + wc];
        float4 wb = *(const float4*)&W[(size_t)(k0 + wr)*CH + bn + wc + 4];
        XsT[xk+0][xr] = xa.x; XsT[xk+1][xr] = xa.y;
        XsT[xk+2][xr] = xa.z; XsT[xk+3][xr] = xa.w;
        XsT[xk+4][xr] = xb.x; XsT[xk+5][xr] = xb.y;
        XsT[xk+6][xr] = xb.z; XsT[xk+7][xr] = xb.w;
        *(float4*)&Ws[wr][wc]     = wa;
        *(float4*)&Ws[wr][wc + 4] = wb;
        __syncthreads();

        #pragma unroll
        for (int kk = 0; kk < 16; kk++) {
            float4 a0 = *(const float4*)&XsT[kk][rg*8];
            float4 a1 = *(const float4*)&XsT[kk][rg*8 + 4];
            float4 b0 = *(const float4*)&Ws[kk][cg*8];
            float4 b1 = *(const float4*)&Ws[kk][cg*8 + 4];
            float a[8] = {a0.x,a0.y,a0.z,a0.w,a1.x,a1.y,a1.z,a1.w};
            float b[8] = {b0.x,b0.y,b0.z,b0.w,b1.x,b1.y,b1.z,b1.w};
            #pragma unroll
            for (int i = 0; i < 8; i++)
                #pragma unroll
                for (int jj = 0; jj < 8; jj++) acc[i][jj] += a[i] * b[jj];
        }
        __syncthreads();
    }

    #pragma unroll
    for (int i = 0; i < 8; i++) {
        int row = bm + rg*8 + i;
        float4 o0, o1;
        o0.x = acc[i][0] + Bb[bn + cg*8 + 0];
        o0.y = acc[i][1] + Bb[bn + cg*8 + 1];
        o0.z = acc[i][2] + Bb[bn + cg*8 + 2];
        o0.w = acc[i][3] + Bb[bn + cg*8 + 3];
        o1.x = acc[i][4] + Bb[bn + cg*8 + 4];
        o1.y = acc[i][5] + Bb[bn + cg*8 + 5];
        o1.z = acc[i][6] + Bb[bn + cg*8 + 6];
        o1.w = acc[i][7] + Bb[bn + cg*8 + 7];
        *(float4*)&C[(size_t)row*ldc + bn + cg*8]     = o0;
        *(float4*)&C[(size_t)row*ldc + bn + cg*8 + 4] = o1;
    }
}

// ---------------- edge-softmax aggregation, one wave per node, 2 edges/iter ----------------
// lane layout: head h = lane>>4 owns dims lane*4..lane*4+3 of the 256-wide row
__global__ __launch_bounds__(256) void attn_kernel(
    const float* __restrict__ Q, const float* __restrict__ KV,
    const int* __restrict__ offs, const int* __restrict__ counts,
    const int* __restrict__ csr_src, float* __restrict__ Xout)
{
    int tid = threadIdx.x;
    int wv = tid >> 6, lane = tid & 63;
    // bijective XCD swizzle: grid=8000 (%8==0, q=1000) -> each XCD works 4 consecutive batches
    int bid = blockIdx.x;
    int swz = (bid & 7) * (NNODES/4/8) + (bid >> 3);
    int n = swz * 4 + wv;

    float4 qv = *(const float4*)&Q[(size_t)n*CH + lane*4];
    int start = offs[n], deg = counts[n];

    float m = -INFINITY, l = 0.f;
    float4 acc = {0.f, 0.f, 0.f, 0.f};

    int e = 0;
    for (; e + 1 < deg; e += 2) {
        int s0 = csr_src[start + e];
        int s1 = csr_src[start + e + 1];
        const float4* kv0 = (const float4*)&KV[(size_t)s0*512 + lane*4];
        const float4* kv1 = (const float4*)&KV[(size_t)s1*512 + lane*4];
        float4 k0 = kv0[0], k1 = kv1[0];
        float4 v0 = kv0[64], v1 = kv1[64];   // +256 floats
        float p0 = k0.x*qv.x + k0.y*qv.y + k0.z*qv.z + k0.w*qv.w;
        float p1 = k1.x*qv.x + k1.y*qv.y + k1.z*qv.z + k1.w*qv.w;
        p0 += __shfl_xor(p0, 8, 16); p1 += __shfl_xor(p1, 8, 16);
        p0 += __shfl_xor(p0, 4, 16); p1 += __shfl_xor(p1, 4, 16);
        p0 += __shfl_xor(p0, 2, 16); p1 += __shfl_xor(p1, 2, 16);
        p0 += __shfl_xor(p0, 1, 16); p1 += __shfl_xor(p1, 1, 16);
        float sa = p0 * 0.125f, sb = p1 * 0.125f;
        float mn = fmaxf(m, fmaxf(sa, sb));
        float sc = __expf(m - mn);
        float e0 = __expf(sa - mn);
        float e1 = __expf(sb - mn);
        l = l*sc + e0 + e1;
        acc.x = acc.x*sc + e0*v0.x + e1*v1.x;
        acc.y = acc.y*sc + e0*v0.y + e1*v1.y;
        acc.z = acc.z*sc + e0*v0.z + e1*v1.z;
        acc.w = acc.w*sc + e0*v0.w + e1*v1.w;
        m = mn;
    }
    if (e < deg) {
        int s0 = csr_src[start + e];
        const float4* kv0 = (const float4*)&KV[(size_t)s0*512 + lane*4];
        float4 k0 = kv0[0];
        float4 v0 = kv0[64];
        float p0 = k0.x*qv.x + k0.y*qv.y + k0.z*qv.z + k0.w*qv.w;
        p0 += __shfl_xor(p0, 8, 16);
        p0 += __shfl_xor(p0, 4, 16);
        p0 += __shfl_xor(p0, 2, 16);
        p0 += __shfl_xor(p0, 1, 16);
        float sa = p0 * 0.125f;
        float mn = fmaxf(m, sa);
        float sc = __expf(m - mn);
        float e0 = __expf(sa - mn);
        l = l*sc + e0;
        acc.x = acc.x*sc + e0*v0.x;
        acc.y = acc.y*sc + e0*v0.y;
        acc.z = acc.z*sc + e0*v0.z;
        acc.w = acc.w*sc + e0*v0.w;
        m = mn;
    }
    float inv = (l > 0.f) ? 1.f / l : 0.f;
    float4 o;
    o.x = fmaxf(acc.x*inv, 0.f);
    o.y = fmaxf(acc.y*inv, 0.f);
    o.z = fmaxf(acc.z*inv, 0.f);
    o.w = fmaxf(acc.w*inv, 0.f);
    *(float4*)&Xout[(size_t)n*CH + lane*4] = o;
}

// ---------------- output head ----------------
__global__ __launch_bounds__(64) void out_kernel(
    const float* __restrict__ obs, const float* __restrict__ X,
    const float* __restrict__ ow, const float* __restrict__ ob,
    float* __restrict__ out)
{
    int b = blockIdx.x, lane = threadIdx.x;
    float a = obs[b*OBS_STRIDE + NN*8];
    int agent = (int)fminf(fmaxf(a, 0.f), (float)(NN - 1));
    int g = b*NN + agent;

    float partial[OUTD] = {};
    #pragma unroll
    for (int c = 0; c < 4; c++) {
        int k = c*64 + lane;
        float xv = X[(size_t)g*CH + k];
        #pragma unroll
        for (int j = 0; j < OUTD; j++) partial[j] += xv * ow[k*OUTD + j];
    }
    #pragma unroll
    for (int j = 0; j < OUTD; j++) {
        #pragma unroll
        for (int o = 32; o >= 1; o >>= 1) partial[j] += __shfl_xor(partial[j], o, 64);
    }
    if (lane == 0) {
        #pragma unroll
        for (int j = 0; j < OUTD; j++) out[b*OUTD + j] = partial[j] + ob[j];
    }
}

extern "C" void kernel_launch(void* const* d_in, const int* in_sizes, int n_in,
                              void* d_out, int out_size, void* d_ws, size_t ws_size,
                              hipStream_t stream)
{
    const float* obs    = (const float*)d_in[0];
    const int*   ei     = (const int*)d_in[1];
    const int    E      = in_sizes[1] / 2;
    const float* enc_w1 = (const float*)d_in[2];
    const float* enc_b1 = (const float*)d_in[3];
    const float* enc_w2 = (const float*)d_in[4];
    const float* enc_b2 = (const float*)d_in[5];
    const float* c1_wq  = (const float*)d_in[6];
    const float* c1_bq  = (const float*)d_in[7];
    const float* c1_wk  = (const float*)d_in[8];
    const float* c1_bk  = (const float*)d_in[9];
    const float* c1_wv  = (const float*)d_in[10];
    const float* c1_bv  = (const float*)d_in[11];
    const float* c2_wq  = (const float*)d_in[12];
    const float* c2_bq  = (const float*)d_in[13];
    const float* c2_wk  = (const float*)d_in[14];
    const float* c2_bk  = (const float*)d_in[15];
    const float* c2_wv  = (const float*)d_in[16];
    const float* c2_bv  = (const float*)d_in[17];
    const float* out_w  = (const float*)d_in[18];
    const float* out_b  = (const float*)d_in[19];
    float* dout = (float*)d_out;

    float* ws    = (float*)d_ws;
    float* h_enc = ws;                           // 32000*64
    float* Qb    = h_enc + (size_t)NNODES*HID;   // 32000*256
    float* KVb   = Qb + (size_t)NNODES*CH;       // 32000*512 (K row | V row interleaved)
    float* X1    = KVb + (size_t)NNODES*512;     // 32000*256
    int* counts  = (int*)(X1 + (size_t)NNODES*CH);
    int* offs    = counts + NNODES;
    int* cursor  = offs + NNODES;
    int* csr     = cursor + NNODES;              // E entries

    hipMemsetAsync(counts, 0, NNODES*sizeof(int), stream);
    hipMemsetAsync(cursor, 0, NNODES*sizeof(int), stream);

    int egrid = (E + 255) / 256;
    count_kernel<<<egrid, 256, 0, stream>>>(ei + E, E, counts);
    scan_kernel<<<1, 1024, 0, stream>>>(counts, offs);
    scatter_kernel<<<egrid, 256, 0, stream>>>(ei, E, offs, cursor, csr);

    encoder_kernel<<<NNODES/16, 256, 0, stream>>>(obs, enc_w1, enc_b1, enc_w2, enc_b2, h_enc);

    dim3 ggrid(NNODES/128, CH/128, 3);
    qkv_gemm<HID><<<ggrid, 256, 0, stream>>>(h_enc, c1_wq, c1_bq, c1_wk, c1_bk, c1_wv, c1_bv,
                                             Qb, KVb);
    attn_kernel<<<NNODES/4, 256, 0, stream>>>(Qb, KVb, offs, counts, csr, X1);

    qkv_gemm<CH><<<ggrid, 256, 0, stream>>>(X1, c2_wq, c2_bq, c2_wk, c2_bk, c2_wv, c2_bv,
                                            Qb, KVb);
    attn_kernel<<<NNODES/4, 256, 0, stream>>>(Qb, KVb, offs, counts, csr, X1);

    out_kernel<<<BSZ, 64, 0, stream>>>(obs, X1, out_w, out_b, dout);
}

// Round 8
// 478.435 us; speedup vs baseline: 1.2508x; 1.0104x over previous
//
#include <hip/hip_runtime.h>
#include <math.h>

#define BSZ 32
#define NN 1000
#define NNODES (BSZ*NN)
#define D_IN 6
#define HID 64
#define NH 4
#define CH (NH*HID)   /* 256 */
#define OUTD 5
#define OBS_STRIDE (NN*8+1)  /* 8001 */

// ---------------- encoder: feats(6) -> relu(64) -> relu(64), 16 nodes/block ----------------
__global__ __launch_bounds__(256) void encoder_kernel(
    const float* __restrict__ obs,
    const float* __restrict__ w1, const float* __restrict__ b1,
    const float* __restrict__ w2, const float* __restrict__ b2,
    float* __restrict__ h_out)
{
    __shared__ float W1s[6*64];
    __shared__ float W2s[64*64];
    __shared__ float B1s[64], B2s[64];
    __shared__ float fs[16][6];
    __shared__ float h1s[4][64];

    int tid = threadIdx.x;
    for (int i = tid; i < 6*64; i += 256) W1s[i] = w1[i];
    for (int i = tid; i < 64*64; i += 256) W2s[i] = w2[i];
    if (tid < 64) { B1s[tid] = b1[tid]; B2s[tid] = b2[tid]; }

    int n0 = blockIdx.x * 16;
    if (tid < 96) {
        int node = tid / 6, f = tid % 6;
        int n = n0 + node;
        fs[node][f] = obs[(n/NN)*OBS_STRIDE + (n%NN)*8 + 2 + f];
    }
    int nl = tid >> 6, j = tid & 63;
    __syncthreads();

    #pragma unroll
    for (int p = 0; p < 4; p++) {
        int ln = p*4 + nl;
        float acc = B1s[j];
        #pragma unroll
        for (int i = 0; i < 6; i++) acc += fs[ln][i] * W1s[i*64 + j];
        h1s[nl][j] = fmaxf(acc, 0.f);
        __syncthreads();
        float acc2 = B2s[j];
        #pragma unroll
        for (int i = 0; i < 64; i++) acc2 += h1s[nl][i] * W2s[i*64 + j];
        h_out[(size_t)(n0 + ln)*64 + j] = fmaxf(acc2, 0.f);
        __syncthreads();
    }
}

// ---------------- CSR build ----------------
__global__ void count_kernel(const int* __restrict__ dst, int E, int* __restrict__ counts)
{
    int e = blockIdx.x * 256 + threadIdx.x;
    if (e < E) atomicAdd(&counts[dst[e]], 1);
}

__global__ __launch_bounds__(1024) void scan_kernel(
    const int* __restrict__ counts, int* __restrict__ offs)
{
    __shared__ int ps[1024];
    int t = threadIdx.x;
    int base = t * 32;
    int s = 0;
    #pragma unroll 4
    for (int i = 0; i < 32; i++) { int idx = base + i; if (idx < NNODES) s += counts[idx]; }
    ps[t] = s;
    __syncthreads();
    for (int o = 1; o < 1024; o <<= 1) {
        int v = (t >= o) ? ps[t - o] : 0;
        __syncthreads();
        ps[t] += v;
        __syncthreads();
    }
    int off = ps[t] - s;   // exclusive
    for (int i = 0; i < 32; i++) {
        int idx = base + i;
        if (idx < NNODES) { offs[idx] = off; off += counts[idx]; }
    }
}

__global__ void scatter_kernel(const int* __restrict__ ei, int E,
                               const int* __restrict__ offs,
                               int* __restrict__ cursor, int* __restrict__ csr_src)
{
    int e = blockIdx.x * 256 + threadIdx.x;
    if (e < E) {
        int s = ei[e];
        int d = ei[E + e];
        int p = offs[d] + atomicAdd(&cursor[d], 1);
        csr_src[p] = s;
    }
}

// ---------------- QKV GEMM: 128x128 tile, 8x8/thread, transposed-X LDS ----------------
// B-fragment = two float4 groups at cols cg*4 and 64+cg*4 (16B stride -> 2-way LDS, free)
// z=0 -> Q (ld 256), z=1 -> K rows of KV (ld 512), z=2 -> V rows of KV (ld 512, +256)
template<int K>
__global__ __launch_bounds__(256) void qkv_gemm(
    const float* __restrict__ X,
    const float* __restrict__ wq, const float* __restrict__ bq,
    const float* __restrict__ wk, const float* __restrict__ bk,
    const float* __restrict__ wv, const float* __restrict__ bv,
    float* __restrict__ Q, float* __restrict__ KV)
{
    const float* W; const float* Bb; float* C; int ldc;
    int z = blockIdx.z;
    if (z == 0)      { W = wq; Bb = bq; C = Q;        ldc = CH;  }
    else if (z == 1) { W = wk; Bb = bk; C = KV;       ldc = 512; }
    else             { W = wv; Bb = bv; C = KV + 256; ldc = 512; }

    __shared__ float XsT[16][132];  // transposed X tile: [k][row]; write 2-way (free), read broadcast
    __shared__ float Ws[16][128];

    int tid = threadIdx.x;
    int bm = blockIdx.x * 128;
    int bn = blockIdx.y * 128;

    // staging indices
    int xr = tid >> 1, xk = (tid & 1) * 8;       // X: row, k-offset (8 floats)
    int wr = tid >> 4, wc4 = (tid & 15) * 4;     // W: k-row, col-offset (two float4s, +0 / +64)
    // compute indices
    int rg = tid >> 4, cg = tid & 15;            // 8-row group, col group (cg*4 and 64+cg*4)

    float acc[8][8] = {};

    for (int k0 = 0; k0 < K; k0 += 16) {
        float4 xa = *(const float4*)&X[(size_t)(bm + xr)*K + k0 + xk];
        float4 xb = *(const float4*)&X[(size_t)(bm + xr)*K + k0 + xk + 4];
        float4 wa = *(const float4*)&W[(size_t)(k0 + wr)*CH + bn + wc4];
        float4 wb = *(const float4*)&W[(size_t)(k0 + wr)*CH + bn + wc4 + 64];
        XsT[xk+0][xr] = xa.x; XsT[xk+1][xr] = xa.y;
        XsT[xk+2][xr] = xa.z; XsT[xk+3][xr] = xa.w;
        XsT[xk+4][xr] = xb.x; XsT[xk+5][xr] = xb.y;
        XsT[xk+6][xr] = xb.z; XsT[xk+7][xr] = xb.w;
        *(float4*)&Ws[wr][wc4]      = wa;   // 16B stride across lanes -> 2-way, free
        *(float4*)&Ws[wr][wc4 + 64] = wb;
        __syncthreads();

        #pragma unroll
        for (int kk = 0; kk < 16; kk++) {
            float4 a0 = *(const float4*)&XsT[kk][rg*8];        // broadcast within quarter-wave
            float4 a1 = *(const float4*)&XsT[kk][rg*8 + 4];
            float4 b0 = *(const float4*)&Ws[kk][cg*4];         // 16B stride -> 2-way, free
            float4 b1 = *(const float4*)&Ws[kk][cg*4 + 64];
            float a[8] = {a0.x,a0.y,a0.z,a0.w,a1.x,a1.y,a1.z,a1.w};
            float b[8] = {b0.x,b0.y,b0.z,b0.w,b1.x,b1.y,b1.z,b1.w};
            #pragma unroll
            for (int i = 0; i < 8; i++)
                #pragma unroll
                for (int jj = 0; jj < 8; jj++) acc[i][jj] += a[i] * b[jj];
        }
        __syncthreads();
    }

    #pragma unroll
    for (int i = 0; i < 8; i++) {
        int row = bm + rg*8 + i;
        float4 o0, o1;
        o0.x = acc[i][0] + Bb[bn + cg*4 + 0];
        o0.y = acc[i][1] + Bb[bn + cg*4 + 1];
        o0.z = acc[i][2] + Bb[bn + cg*4 + 2];
        o0.w = acc[i][3] + Bb[bn + cg*4 + 3];
        o1.x = acc[i][4] + Bb[bn + 64 + cg*4 + 0];
        o1.y = acc[i][5] + Bb[bn + 64 + cg*4 + 1];
        o1.z = acc[i][6] + Bb[bn + 64 + cg*4 + 2];
        o1.w = acc[i][7] + Bb[bn + 64 + cg*4 + 3];
        *(float4*)&C[(size_t)row*ldc + bn + cg*4]      = o0;
        *(float4*)&C[(size_t)row*ldc + bn + 64 + cg*4] = o1;
    }
}

// ---------------- edge-softmax aggregation, one wave per node, 2 edges/iter ----------------
// lane layout: head h = lane>>4 owns dims lane*4..lane*4+3 of the 256-wide row
__global__ __launch_bounds__(256) void attn_kernel(
    const float* __restrict__ Q, const float* __restrict__ KV,
    const int* __restrict__ offs, const int* __restrict__ counts,
    const int* __restrict__ csr_src, float* __restrict__ Xout)
{
    int tid = threadIdx.x;
    int wv = tid >> 6, lane = tid & 63;
    // bijective XCD swizzle: grid=8000 (%8==0, q=1000) -> each XCD works 4 consecutive batches
    int bid = blockIdx.x;
    int swz = (bid & 7) * (NNODES/4/8) + (bid >> 3);
    int n = swz * 4 + wv;

    float4 qv = *(const float4*)&Q[(size_t)n*CH + lane*4];
    int start = offs[n], deg = counts[n];

    float m = -INFINITY, l = 0.f;
    float4 acc = {0.f, 0.f, 0.f, 0.f};

    int e = 0;
    for (; e + 1 < deg; e += 2) {
        int s0 = csr_src[start + e];
        int s1 = csr_src[start + e + 1];
        const float4* kv0 = (const float4*)&KV[(size_t)s0*512 + lane*4];
        const float4* kv1 = (const float4*)&KV[(size_t)s1*512 + lane*4];
        float4 k0 = kv0[0], k1 = kv1[0];
        float4 v0 = kv0[64], v1 = kv1[64];   // +256 floats
        float p0 = k0.x*qv.x + k0.y*qv.y + k0.z*qv.z + k0.w*qv.w;
        float p1 = k1.x*qv.x + k1.y*qv.y + k1.z*qv.z + k1.w*qv.w;
        p0 += __shfl_xor(p0, 8, 16); p1 += __shfl_xor(p1, 8, 16);
        p0 += __shfl_xor(p0, 4, 16); p1 += __shfl_xor(p1, 4, 16);
        p0 += __shfl_xor(p0, 2, 16); p1 += __shfl_xor(p1, 2, 16);
        p0 += __shfl_xor(p0, 1, 16); p1 += __shfl_xor(p1, 1, 16);
        float sa = p0 * 0.125f, sb = p1 * 0.125f;
        float mn = fmaxf(m, fmaxf(sa, sb));
        float sc = __expf(m - mn);
        float e0 = __expf(sa - mn);
        float e1 = __expf(sb - mn);
        l = l*sc + e0 + e1;
        acc.x = acc.x*sc + e0*v0.x + e1*v1.x;
        acc.y = acc.y*sc + e0*v0.y + e1*v1.y;
        acc.z = acc.z*sc + e0*v0.z + e1*v1.z;
        acc.w = acc.w*sc + e0*v0.w + e1*v1.w;
        m = mn;
    }
    if (e < deg) {
        int s0 = csr_src[start + e];
        const float4* kv0 = (const float4*)&KV[(size_t)s0*512 + lane*4];
        float4 k0 = kv0[0];
        float4 v0 = kv0[64];
        float p0 = k0.x*qv.x + k0.y*qv.y + k0.z*qv.z + k0.w*qv.w;
        p0 += __shfl_xor(p0, 8, 16);
        p0 += __shfl_xor(p0, 4, 16);
        p0 += __shfl_xor(p0, 2, 16);
        p0 += __shfl_xor(p0, 1, 16);
        float sa = p0 * 0.125f;
        float mn = fmaxf(m, sa);
        float sc = __expf(m - mn);
        float e0 = __expf(sa - mn);
        l = l*sc + e0;
        acc.x = acc.x*sc + e0*v0.x;
        acc.y = acc.y*sc + e0*v0.y;
        acc.z = acc.z*sc + e0*v0.z;
        acc.w = acc.w*sc + e0*v0.w;
        m = mn;
    }
    float inv = (l > 0.f) ? 1.f / l : 0.f;
    float4 o;
    o.x = fmaxf(acc.x*inv, 0.f);
    o.y = fmaxf(acc.y*inv, 0.f);
    o.z = fmaxf(acc.z*inv, 0.f);
    o.w = fmaxf(acc.w*inv, 0.f);
    *(float4*)&Xout[(size_t)n*CH + lane*4] = o;
}

// ---------------- output head ----------------
__global__ __launch_bounds__(64) void out_kernel(
    const float* __restrict__ obs, const float* __restrict__ X,
    const float* __restrict__ ow, const float* __restrict__ ob,
    float* __restrict__ out)
{
    int b = blockIdx.x, lane = threadIdx.x;
    float a = obs[b*OBS_STRIDE + NN*8];
    int agent = (int)fminf(fmaxf(a, 0.f), (float)(NN - 1));
    int g = b*NN + agent;

    float partial[OUTD] = {};
    #pragma unroll
    for (int c = 0; c < 4; c++) {
        int k = c*64 + lane;
        float xv = X[(size_t)g*CH + k];
        #pragma unroll
        for (int j = 0; j < OUTD; j++) partial[j] += xv * ow[k*OUTD + j];
    }
    #pragma unroll
    for (int j = 0; j < OUTD; j++) {
        #pragma unroll
        for (int o = 32; o >= 1; o >>= 1) partial[j] += __shfl_xor(partial[j], o, 64);
    }
    if (lane == 0) {
        #pragma unroll
        for (int j = 0; j < OUTD; j++) out[b*OUTD + j] = partial[j] + ob[j];
    }
}

extern "C" void kernel_launch(void* const* d_in, const int* in_sizes, int n_in,
                              void* d_out, int out_size, void* d_ws, size_t ws_size,
                              hipStream_t stream)
{
    const float* obs    = (const float*)d_in[0];
    const int*   ei     = (const int*)d_in[1];
    const int    E      = in_sizes[1] / 2;
    const float* enc_w1 = (const float*)d_in[2];
    const float* enc_b1 = (const float*)d_in[3];
    const float* enc_w2 = (const float*)d_in[4];
    const float* enc_b2 = (const float*)d_in[5];
    const float* c1_wq  = (const float*)d_in[6];
    const float* c1_bq  = (const float*)d_in[7];
    const float* c1_wk  = (const float*)d_in[8];
    const float* c1_bk  = (const float*)d_in[9];
    const float* c1_wv  = (const float*)d_in[10];
    const float* c1_bv  = (const float*)d_in[11];
    const float* c2_wq  = (const float*)d_in[12];
    const float* c2_bq  = (const float*)d_in[13];
    const float* c2_wk  = (const float*)d_in[14];
    const float* c2_bk  = (const float*)d_in[15];
    const float* c2_wv  = (const float*)d_in[16];
    const float* c2_bv  = (const float*)d_in[17];
    const float* out_w  = (const float*)d_in[18];
    const float* out_b  = (const float*)d_in[19];
    float* dout = (float*)d_out;

    float* ws    = (float*)d_ws;
    float* h_enc = ws;                           // 32000*64
    float* Qb    = h_enc + (size_t)NNODES*HID;   // 32000*256
    float* KVb   = Qb + (size_t)NNODES*CH;       // 32000*512 (K row | V row interleaved)
    float* X1    = KVb + (size_t)NNODES*512;     // 32000*256
    int* counts  = (int*)(X1 + (size_t)NNODES*CH);
    int* offs    = counts + NNODES;
    int* cursor  = offs + NNODES;
    int* csr     = cursor + NNODES;              // E entries

    hipMemsetAsync(counts, 0, NNODES*sizeof(int), stream);
    hipMemsetAsync(cursor, 0, NNODES*sizeof(int), stream);

    int egrid = (E + 255) / 256;
    count_kernel<<<egrid, 256, 0, stream>>>(ei + E, E, counts);
    scan_kernel<<<1, 1024, 0, stream>>>(counts, offs);
    scatter_kernel<<<egrid, 256, 0, stream>>>(ei, E, offs, cursor, csr);

    encoder_kernel<<<NNODES/16, 256, 0, stream>>>(obs, enc_w1, enc_b1, enc_w2, enc_b2, h_enc);

    dim3 ggrid(NNODES/128, CH/128, 3);
    qkv_gemm<HID><<<ggrid, 256, 0, stream>>>(h_enc, c1_wq, c1_bq, c1_wk, c1_bk, c1_wv, c1_bv,
                                             Qb, KVb);
    attn_kernel<<<NNODES/4, 256, 0, stream>>>(Qb, KVb, offs, counts, csr, X1);

    qkv_gemm<CH><<<ggrid, 256, 0, stream>>>(X1, c2_wq, c2_bq, c2_wk, c2_bk, c2_wv, c2_bv,
                                            Qb, KVb);
    attn_kernel<<<NNODES/4, 256, 0, stream>>>(Qb, KVb, offs, counts, csr, X1);

    out_kernel<<<BSZ, 64, 0, stream>>>(obs, X1, out_w, out_b, dout);
}

// Round 12
// 399.416 us; speedup vs baseline: 1.4983x; 1.1978x over previous
//
#include <hip/hip_runtime.h>
#include <math.h>

#define BSZ 32
#define NN 1000
#define NNODES (BSZ*NN)
#define D_IN 6
#define HID 64
#define NH 4
#define CH (NH*HID)   /* 256 */
#define OUTD 5
#define OBS_STRIDE (NN*8+1)  /* 8001 */

typedef _Float16 f16x8 __attribute__((ext_vector_type(8)));
typedef _Float16 f16x4 __attribute__((ext_vector_type(4)));
typedef float f32x4 __attribute__((ext_vector_type(4)));

#define AS1(p) ((const __attribute__((address_space(1))) void*)(p))
#define AS3(p) ((__attribute__((address_space(3))) void*)(p))

// ---------------- encoder: feats(6) -> relu(64) -> relu(64), emits f16 hi/lo ----------------
__global__ __launch_bounds__(256) void encoder_kernel(
    const float* __restrict__ obs,
    const float* __restrict__ w1, const float* __restrict__ b1,
    const float* __restrict__ w2, const float* __restrict__ b2,
    _Float16* __restrict__ h_hi, _Float16* __restrict__ h_lo)
{
    __shared__ float W1s[6*64];
    __shared__ float W2s[64*64];
    __shared__ float B1s[64], B2s[64];
    __shared__ float fs[16][6];
    __shared__ float h1s[4][64];

    int tid = threadIdx.x;
    for (int i = tid; i < 6*64; i += 256) W1s[i] = w1[i];
    for (int i = tid; i < 64*64; i += 256) W2s[i] = w2[i];
    if (tid < 64) { B1s[tid] = b1[tid]; B2s[tid] = b2[tid]; }

    int n0 = blockIdx.x * 16;
    if (tid < 96) {
        int node = tid / 6, f = tid % 6;
        int n = n0 + node;
        fs[node][f] = obs[(n/NN)*OBS_STRIDE + (n%NN)*8 + 2 + f];
    }
    int nl = tid >> 6, j = tid & 63;
    __syncthreads();

    #pragma unroll
    for (int p = 0; p < 4; p++) {
        int ln = p*4 + nl;
        float acc = B1s[j];
        #pragma unroll
        for (int i = 0; i < 6; i++) acc += fs[ln][i] * W1s[i*64 + j];
        h1s[nl][j] = fmaxf(acc, 0.f);
        __syncthreads();
        float acc2 = B2s[j];
        #pragma unroll
        for (int i = 0; i < 64; i++) acc2 += h1s[nl][i] * W2s[i*64 + j];
        float v = fmaxf(acc2, 0.f);
        _Float16 hh = (_Float16)v;
        _Float16 hl = (_Float16)(v - (float)hh);
        h_hi[(size_t)(n0 + ln)*64 + j] = hh;
        h_lo[(size_t)(n0 + ln)*64 + j] = hl;
        __syncthreads();
    }
}

// ---------------- weight split+transpose: W[K][256] f32 -> WT[256][K] f16 hi/lo ----------------
__global__ __launch_bounds__(64) void split_wt_kernel(
    const float* __restrict__ w0, const float* __restrict__ w1, const float* __restrict__ w2,
    const float* __restrict__ w3, const float* __restrict__ w4, const float* __restrict__ w5,
    _Float16* __restrict__ hi_c1, _Float16* __restrict__ lo_c1,
    _Float16* __restrict__ hi_c2, _Float16* __restrict__ lo_c2)
{
    int z = blockIdx.z;
    int col = blockIdx.x;
    int t = threadIdx.x;
    const float* W; int Kd; _Float16 *dh, *dl;
    if (z < 3) { W = (z==0 ? w0 : z==1 ? w1 : w2); Kd = 64;
                 dh = hi_c1 + (size_t)z*256*64;  dl = lo_c1 + (size_t)z*256*64; }
    else       { W = (z==3 ? w3 : z==4 ? w4 : w5); Kd = 256;
                 dh = hi_c2 + (size_t)(z-3)*256*256; dl = lo_c2 + (size_t)(z-3)*256*256; }
    for (int k = t; k < Kd; k += 64) {
        float x = W[(size_t)k*256 + col];
        _Float16 h = (_Float16)x;
        dh[(size_t)col*Kd + k] = h;
        dl[(size_t)col*Kd + k] = (_Float16)(x - (float)h);
    }
}

// ---------------- CSR build ----------------
__global__ void count_kernel(const int* __restrict__ dst, int E, int* __restrict__ counts)
{
    int e = blockIdx.x * 256 + threadIdx.x;
    if (e < E) atomicAdd(&counts[dst[e]], 1);
}

__global__ __launch_bounds__(1024) void scan_kernel(
    const int* __restrict__ counts, int* __restrict__ offs)
{
    __shared__ int ps[1024];
    int t = threadIdx.x;
    int base = t * 32;
    int s = 0;
    #pragma unroll 4
    for (int i = 0; i < 32; i++) { int idx = base + i; if (idx < NNODES) s += counts[idx]; }
    ps[t] = s;
    __syncthreads();
    for (int o = 1; o < 1024; o <<= 1) {
        int v = (t >= o) ? ps[t - o] : 0;
        __syncthreads();
        ps[t] += v;
        __syncthreads();
    }
    int off = ps[t] - s;   // exclusive
    for (int i = 0; i < 32; i++) {
        int idx = base + i;
        if (idx < NNODES) { offs[idx] = off; off += counts[idx]; }
    }
}

__global__ void scatter_kernel(const int* __restrict__ ei, int E,
                               const int* __restrict__ offs,
                               int* __restrict__ cursor, int* __restrict__ csr_src)
{
    int e = blockIdx.x * 256 + threadIdx.x;
    if (e < E) {
        int s = ei[e];
        int d = ei[E + e];
        int p = offs[d] + atomicAdd(&cursor[d], 1);
        csr_src[p] = s;
    }
}

// ---------------- QKV GEMM via f16x2-split MFMA ----------------
// C = X@W + b computed as Xhi@Whi + Xhi@Wlo + Xlo@Whi (f16 MFMA, f32 accum).
// X[hi/lo]: [M][K] f16; WT[hi/lo]: [3][256][K] f16 (pre-transposed).
// 128x128 tile, 4 waves, each wave a 64x64 sub-tile of 4x4 16x16 fragments.
// LDS linear [128][32] f16 (64B rows): fragment reads are bank-minimal; staged
// via global_load_lds width-16 (m97 structure).
template<int K>
__global__ __launch_bounds__(256) void qkv_gemm_mfma(
    const _Float16* __restrict__ Xhi, const _Float16* __restrict__ Xlo,
    const _Float16* __restrict__ WThi, const _Float16* __restrict__ WTlo,
    const float* __restrict__ bq, const float* __restrict__ bk, const float* __restrict__ bv,
    float* __restrict__ Q, float* __restrict__ KV)
{
    const float* Bb; float* C; int ldc;
    int z = blockIdx.z;
    if (z == 0)      { Bb = bq; C = Q;        ldc = CH;  }
    else if (z == 1) { Bb = bk; C = KV;       ldc = 512; }
    else             { Bb = bv; C = KV + 256; ldc = 512; }
    const _Float16* Whi = WThi + (size_t)z*256*K;
    const _Float16* Wlo = WTlo + (size_t)z*256*K;

    __shared__ _Float16 As_hi[128*32];
    __shared__ _Float16 As_lo[128*32];
    __shared__ _Float16 Bs_hi[128*32];
    __shared__ _Float16 Bs_lo[128*32];

    int tid = threadIdx.x;
    int wv = tid >> 6, l = tid & 63;
    int bm = blockIdx.x * 128, bn = blockIdx.y * 128;

    // staging: wave wv covers rows wv*32..wv*32+31 (two 16-row instructions per buffer)
    int srow = wv*32 + (l >> 2);
    size_t gxa = (size_t)(bm + srow)*K + (l & 3)*8;
    size_t gwb = (size_t)(bn + srow)*K + (l & 3)*8;
    int loff = wv*2048 + l*16;   // byte offset in LDS tile

    // compute: wave (wr,wc) sub-tile
    int wr = wv >> 1, wc = wv & 1;
    int fr = l & 15, fk = l >> 4;

    f32x4 acc[4][4] = {};

    for (int k0 = 0; k0 < K; k0 += 32) {
        __syncthreads();   // previous iteration's readers done
        const _Float16* ga = Xhi + gxa + k0;
        const _Float16* gb = Xlo + gxa + k0;
        const _Float16* gc = Whi + gwb + k0;
        const _Float16* gd = Wlo + gwb + k0;
        __builtin_amdgcn_global_load_lds(AS1(ga),            AS3((char*)As_hi + loff),        16, 0, 0);
        __builtin_amdgcn_global_load_lds(AS1(ga + 16*(size_t)K), AS3((char*)As_hi + loff + 1024), 16, 0, 0);
        __builtin_amdgcn_global_load_lds(AS1(gb),            AS3((char*)As_lo + loff),        16, 0, 0);
        __builtin_amdgcn_global_load_lds(AS1(gb + 16*(size_t)K), AS3((char*)As_lo + loff + 1024), 16, 0, 0);
        __builtin_amdgcn_global_load_lds(AS1(gc),            AS3((char*)Bs_hi + loff),        16, 0, 0);
        __builtin_amdgcn_global_load_lds(AS1(gc + 16*(size_t)K), AS3((char*)Bs_hi + loff + 1024), 16, 0, 0);
        __builtin_amdgcn_global_load_lds(AS1(gd),            AS3((char*)Bs_lo + loff),        16, 0, 0);
        __builtin_amdgcn_global_load_lds(AS1(gd + 16*(size_t)K), AS3((char*)Bs_lo + loff + 1024), 16, 0, 0);
        __syncthreads();   // compiler drains vmcnt(0) before this barrier

        f16x8 ah[4], al[4], bh[4], bl[4];
        #pragma unroll
        for (int m = 0; m < 4; m++) {
            int rb = (wr*64 + m*16 + fr)*64 + fk*16;
            ah[m] = *(const f16x8*)((const char*)As_hi + rb);
            al[m] = *(const f16x8*)((const char*)As_lo + rb);
        }
        #pragma unroll
        for (int n = 0; n < 4; n++) {
            int rb = (wc*64 + n*16 + fr)*64 + fk*16;
            bh[n] = *(const f16x8*)((const char*)Bs_hi + rb);
            bl[n] = *(const f16x8*)((const char*)Bs_lo + rb);
        }
        #pragma unroll
        for (int m = 0; m < 4; m++)
            #pragma unroll
            for (int n = 0; n < 4; n++) {
                acc[m][n] = __builtin_amdgcn_mfma_f32_16x16x32_f16(ah[m], bh[n], acc[m][n], 0, 0, 0);
                acc[m][n] = __builtin_amdgcn_mfma_f32_16x16x32_f16(ah[m], bl[n], acc[m][n], 0, 0, 0);
                acc[m][n] = __builtin_amdgcn_mfma_f32_16x16x32_f16(al[m], bh[n], acc[m][n], 0, 0, 0);
            }
    }

    // epilogue: D col=lane&15, row=(lane>>4)*4+reg (m89-verified mapping)
    #pragma unroll
    for (int n = 0; n < 4; n++) {
        int c = bn + wc*64 + n*16 + fr;
        float bb = Bb[c];
        #pragma unroll
        for (int m = 0; m < 4; m++) {
            int rbase = bm + wr*64 + m*16 + fk*4;
            #pragma unroll
            for (int r = 0; r < 4; r++) {
                C[(size_t)(rbase + r)*ldc + c] = acc[m][n][r] + bb;
            }
        }
    }
}

// ---------------- edge-softmax aggregation, one wave per node, 2 edges/iter ----------------
// writes f16 hi/lo (consumed by next GEMM / output head)
__global__ __launch_bounds__(256) void attn_kernel(
    const float* __restrict__ Q, const float* __restrict__ KV,
    const int* __restrict__ offs, const int* __restrict__ counts,
    const int* __restrict__ csr_src,
    _Float16* __restrict__ X1hi, _Float16* __restrict__ X1lo)
{
    int tid = threadIdx.x;
    int wv = tid >> 6, lane = tid & 63;
    int bid = blockIdx.x;
    int swz = (bid & 7) * (NNODES/4/8) + (bid >> 3);
    int n = swz * 4 + wv;

    float4 qv = *(const float4*)&Q[(size_t)n*CH + lane*4];
    int start = offs[n], deg = counts[n];

    float m = -INFINITY, l = 0.f;
    float4 acc = {0.f, 0.f, 0.f, 0.f};

    int e = 0;
    for (; e + 1 < deg; e += 2) {
        int s0 = csr_src[start + e];
        int s1 = csr_src[start + e + 1];
        const float4* kv0 = (const float4*)&KV[(size_t)s0*512 + lane*4];
        const float4* kv1 = (const float4*)&KV[(size_t)s1*512 + lane*4];
        float4 k0 = kv0[0], k1 = kv1[0];
        float4 v0 = kv0[64], v1 = kv1[64];
        float p0 = k0.x*qv.x + k0.y*qv.y + k0.z*qv.z + k0.w*qv.w;
        float p1 = k1.x*qv.x + k1.y*qv.y + k1.z*qv.z + k1.w*qv.w;
        p0 += __shfl_xor(p0, 8, 16); p1 += __shfl_xor(p1, 8, 16);
        p0 += __shfl_xor(p0, 4, 16); p1 += __shfl_xor(p1, 4, 16);
        p0 += __shfl_xor(p0, 2, 16); p1 += __shfl_xor(p1, 2, 16);
        p0 += __shfl_xor(p0, 1, 16); p1 += __shfl_xor(p1, 1, 16);
        float sa = p0 * 0.125f, sb = p1 * 0.125f;
        float mn = fmaxf(m, fmaxf(sa, sb));
        float sc = __expf(m - mn);
        float e0 = __expf(sa - mn);
        float e1 = __expf(sb - mn);
        l = l*sc + e0 + e1;
        acc.x = acc.x*sc + e0*v0.x + e1*v1.x;
        acc.y = acc.y*sc + e0*v0.y + e1*v1.y;
        acc.z = acc.z*sc + e0*v0.z + e1*v1.z;
        acc.w = acc.w*sc + e0*v0.w + e1*v1.w;
        m = mn;
    }
    if (e < deg) {
        int s0 = csr_src[start + e];
        const float4* kv0 = (const float4*)&KV[(size_t)s0*512 + lane*4];
        float4 k0 = kv0[0];
        float4 v0 = kv0[64];
        float p0 = k0.x*qv.x + k0.y*qv.y + k0.z*qv.z + k0.w*qv.w;
        p0 += __shfl_xor(p0, 8, 16);
        p0 += __shfl_xor(p0, 4, 16);
        p0 += __shfl_xor(p0, 2, 16);
        p0 += __shfl_xor(p0, 1, 16);
        float sa = p0 * 0.125f;
        float mn = fmaxf(m, sa);
        float sc = __expf(m - mn);
        float e0 = __expf(sa - mn);
        l = l*sc + e0;
        acc.x = acc.x*sc + e0*v0.x;
        acc.y = acc.y*sc + e0*v0.y;
        acc.z = acc.z*sc + e0*v0.z;
        acc.w = acc.w*sc + e0*v0.w;
        m = mn;
    }
    float inv = (l > 0.f) ? 1.f / l : 0.f;
    float o0 = fmaxf(acc.x*inv, 0.f);
    float o1 = fmaxf(acc.y*inv, 0.f);
    float o2 = fmaxf(acc.z*inv, 0.f);
    float o3 = fmaxf(acc.w*inv, 0.f);
    _Float16 h0 = (_Float16)o0, h1 = (_Float16)o1, h2 = (_Float16)o2, h3 = (_Float16)o3;
    f16x4 vh = {h0, h1, h2, h3};
    f16x4 vl = {(_Float16)(o0 - (float)h0), (_Float16)(o1 - (float)h1),
                (_Float16)(o2 - (float)h2), (_Float16)(o3 - (float)h3)};
    *(f16x4*)&X1hi[(size_t)n*CH + lane*4] = vh;
    *(f16x4*)&X1lo[(size_t)n*CH + lane*4] = vl;
}

// ---------------- output head: x = hi + lo reconstruction ----------------
__global__ __launch_bounds__(64) void out_kernel(
    const float* __restrict__ obs,
    const _Float16* __restrict__ X1hi, const _Float16* __restrict__ X1lo,
    const float* __restrict__ ow, const float* __restrict__ ob,
    float* __restrict__ out)
{
    int b = blockIdx.x, lane = threadIdx.x;
    float a = obs[b*OBS_STRIDE + NN*8];
    int agent = (int)fminf(fmaxf(a, 0.f), (float)(NN - 1));
    int g = b*NN + agent;

    float partial[OUTD] = {};
    #pragma unroll
    for (int c = 0; c < 4; c++) {
        int k = c*64 + lane;
        size_t idx = (size_t)g*CH + k;
        float xv = (float)X1hi[idx] + (float)X1lo[idx];
        #pragma unroll
        for (int j = 0; j < OUTD; j++) partial[j] += xv * ow[k*OUTD + j];
    }
    #pragma unroll
    for (int j = 0; j < OUTD; j++) {
        #pragma unroll
        for (int o = 32; o >= 1; o >>= 1) partial[j] += __shfl_xor(partial[j], o, 64);
    }
    if (lane == 0) {
        #pragma unroll
        for (int j = 0; j < OUTD; j++) out[b*OUTD + j] = partial[j] + ob[j];
    }
}

extern "C" void kernel_launch(void* const* d_in, const int* in_sizes, int n_in,
                              void* d_out, int out_size, void* d_ws, size_t ws_size,
                              hipStream_t stream)
{
    const float* obs    = (const float*)d_in[0];
    const int*   ei     = (const int*)d_in[1];
    const int    E      = in_sizes[1] / 2;
    const float* enc_w1 = (const float*)d_in[2];
    const float* enc_b1 = (const float*)d_in[3];
    const float* enc_w2 = (const float*)d_in[4];
    const float* enc_b2 = (const float*)d_in[5];
    const float* c1_wq  = (const float*)d_in[6];
    const float* c1_bq  = (const float*)d_in[7];
    const float* c1_wk  = (const float*)d_in[8];
    const float* c1_bk  = (const float*)d_in[9];
    const float* c1_wv  = (const float*)d_in[10];
    const float* c1_bv  = (const float*)d_in[11];
    const float* c2_wq  = (const float*)d_in[12];
    const float* c2_bq  = (const float*)d_in[13];
    const float* c2_wk  = (const float*)d_in[14];
    const float* c2_bk  = (const float*)d_in[15];
    const float* c2_wv  = (const float*)d_in[16];
    const float* c2_bv  = (const float*)d_in[17];
    const float* out_w  = (const float*)d_in[18];
    const float* out_b  = (const float*)d_in[19];
    float* dout = (float*)d_out;

    // workspace layout (~137 MB)
    float* ws   = (float*)d_ws;
    float* Qb   = ws;                                   // 32000*256 f32
    float* KVb  = Qb + (size_t)NNODES*CH;               // 32000*512 f32 (K|V interleaved)
    _Float16* X1hi = (_Float16*)(KVb + (size_t)NNODES*512);  // 32000*256 f16
    _Float16* X1lo = X1hi + (size_t)NNODES*CH;               // 32000*256 f16
    _Float16* h_hi = X1hi;   // alias: encoder output (32000*64) dead before attn1 writes X1hi
    _Float16* h_lo = X1lo;
    _Float16* wt_hi_c1 = X1lo + (size_t)NNODES*CH;      // 3*256*64
    _Float16* wt_lo_c1 = wt_hi_c1 + 3*256*64;
    _Float16* wt_hi_c2 = wt_lo_c1 + 3*256*64;           // 3*256*256
    _Float16* wt_lo_c2 = wt_hi_c2 + 3*256*256;
    int* counts = (int*)(wt_lo_c2 + 3*256*256);
    int* offs   = counts + NNODES;
    int* cursor = offs + NNODES;
    int* csr    = cursor + NNODES;                      // E entries

    hipMemsetAsync(counts, 0, NNODES*sizeof(int), stream);
    hipMemsetAsync(cursor, 0, NNODES*sizeof(int), stream);

    int egrid = (E + 255) / 256;
    count_kernel<<<egrid, 256, 0, stream>>>(ei + E, E, counts);
    scan_kernel<<<1, 1024, 0, stream>>>(counts, offs);
    scatter_kernel<<<egrid, 256, 0, stream>>>(ei, E, offs, cursor, csr);

    split_wt_kernel<<<dim3(256, 1, 6), 64, 0, stream>>>(
        c1_wq, c1_wk, c1_wv, c2_wq, c2_wk, c2_wv,
        wt_hi_c1, wt_lo_c1, wt_hi_c2, wt_lo_c2);

    encoder_kernel<<<NNODES/16, 256, 0, stream>>>(obs, enc_w1, enc_b1, enc_w2, enc_b2, h_hi, h_lo);

    dim3 ggrid(NNODES/128, CH/128, 3);
    qkv_gemm_mfma<HID><<<ggrid, 256, 0, stream>>>(h_hi, h_lo, wt_hi_c1, wt_lo_c1,
                                                  c1_bq, c1_bk, c1_bv, Qb, KVb);
    attn_kernel<<<NNODES/4, 256, 0, stream>>>(Qb, KVb, offs, counts, csr, X1hi, X1lo);

    qkv_gemm_mfma<CH><<<ggrid, 256, 0, stream>>>(X1hi, X1lo, wt_hi_c2, wt_lo_c2,
                                                 c2_bq, c2_bk, c2_bv, Qb, KVb);
    attn_kernel<<<NNODES/4, 256, 0, stream>>>(Qb, KVb, offs, counts, csr, X1hi, X1lo);

    out_kernel<<<BSZ, 64, 0, stream>>>(obs, X1hi, X1lo, out_w, out_b, dout);
}

// Round 17
// 364.634 us; speedup vs baseline: 1.6412x; 1.0954x over previous
//
#include <hip/hip_runtime.h>
#include <math.h>

#define BSZ 32
#define NN 1000
#define NNODES (BSZ*NN)
#define D_IN 6
#define HID 64
#define NH 4
#define CH (NH*HID)   /* 256 */
#define OUTD 5
#define OBS_STRIDE (NN*8+1)  /* 8001 */

typedef _Float16 f16x8 __attribute__((ext_vector_type(8)));
typedef _Float16 f16x4 __attribute__((ext_vector_type(4)));
typedef float f32x4 __attribute__((ext_vector_type(4)));

#define AS1(p) ((const __attribute__((address_space(1))) void*)(p))
#define AS3(p) ((__attribute__((address_space(3))) void*)(p))

// ---------------- encoder: feats(6) -> relu(64) -> relu(64), emits f16 hi/lo ----------------
__global__ __launch_bounds__(256) void encoder_kernel(
    const float* __restrict__ obs,
    const float* __restrict__ w1, const float* __restrict__ b1,
    const float* __restrict__ w2, const float* __restrict__ b2,
    _Float16* __restrict__ h_hi, _Float16* __restrict__ h_lo)
{
    __shared__ float W1s[6*64];
    __shared__ float W2s[64*64];
    __shared__ float B1s[64], B2s[64];
    __shared__ float fs[16][6];
    __shared__ float h1s[4][64];

    int tid = threadIdx.x;
    for (int i = tid; i < 6*64; i += 256) W1s[i] = w1[i];
    for (int i = tid; i < 64*64; i += 256) W2s[i] = w2[i];
    if (tid < 64) { B1s[tid] = b1[tid]; B2s[tid] = b2[tid]; }

    int n0 = blockIdx.x * 16;
    if (tid < 96) {
        int node = tid / 6, f = tid % 6;
        int n = n0 + node;
        fs[node][f] = obs[(n/NN)*OBS_STRIDE + (n%NN)*8 + 2 + f];
    }
    int nl = tid >> 6, j = tid & 63;
    __syncthreads();

    #pragma unroll
    for (int p = 0; p < 4; p++) {
        int ln = p*4 + nl;
        float acc = B1s[j];
        #pragma unroll
        for (int i = 0; i < 6; i++) acc += fs[ln][i] * W1s[i*64 + j];
        h1s[nl][j] = fmaxf(acc, 0.f);
        __syncthreads();
        float acc2 = B2s[j];
        #pragma unroll
        for (int i = 0; i < 64; i++) acc2 += h1s[nl][i] * W2s[i*64 + j];
        float v = fmaxf(acc2, 0.f);
        _Float16 hh = (_Float16)v;
        _Float16 hl = (_Float16)(v - (float)hh);
        h_hi[(size_t)(n0 + ln)*64 + j] = hh;
        h_lo[(size_t)(n0 + ln)*64 + j] = hl;
        __syncthreads();
    }
}

// ---------------- weight split+transpose: W[K][256] f32 -> WT[256][K] f16 hi/lo ----------------
__global__ __launch_bounds__(64) void split_wt_kernel(
    const float* __restrict__ w0, const float* __restrict__ w1, const float* __restrict__ w2,
    const float* __restrict__ w3, const float* __restrict__ w4, const float* __restrict__ w5,
    _Float16* __restrict__ hi_c1, _Float16* __restrict__ lo_c1,
    _Float16* __restrict__ hi_c2, _Float16* __restrict__ lo_c2)
{
    int z = blockIdx.z;
    int col = blockIdx.x;
    int t = threadIdx.x;
    const float* W; int Kd; _Float16 *dh, *dl;
    if (z < 3) { W = (z==0 ? w0 : z==1 ? w1 : w2); Kd = 64;
                 dh = hi_c1 + (size_t)z*256*64;  dl = lo_c1 + (size_t)z*256*64; }
    else       { W = (z==3 ? w3 : z==4 ? w4 : w5); Kd = 256;
                 dh = hi_c2 + (size_t)(z-3)*256*256; dl = lo_c2 + (size_t)(z-3)*256*256; }
    for (int k = t; k < Kd; k += 64) {
        float x = W[(size_t)k*256 + col];
        _Float16 h = (_Float16)x;
        dh[(size_t)col*Kd + k] = h;
        dl[(size_t)col*Kd + k] = (_Float16)(x - (float)h);
    }
}

// ---------------- CSR build ----------------
__global__ void count_kernel(const int* __restrict__ dst, int E, int* __restrict__ counts)
{
    int e = blockIdx.x * 256 + threadIdx.x;
    if (e < E) atomicAdd(&counts[dst[e]], 1);
}

__global__ __launch_bounds__(1024) void scan_kernel(
    const int* __restrict__ counts, int* __restrict__ offs)
{
    __shared__ int ps[1024];
    int t = threadIdx.x;
    int base = t * 32;
    int s = 0;
    #pragma unroll 4
    for (int i = 0; i < 32; i++) { int idx = base + i; if (idx < NNODES) s += counts[idx]; }
    ps[t] = s;
    __syncthreads();
    for (int o = 1; o < 1024; o <<= 1) {
        int v = (t >= o) ? ps[t - o] : 0;
        __syncthreads();
        ps[t] += v;
        __syncthreads();
    }
    int off = ps[t] - s;   // exclusive
    for (int i = 0; i < 32; i++) {
        int idx = base + i;
        if (idx < NNODES) { offs[idx] = off; off += counts[idx]; }
    }
}

__global__ void scatter_kernel(const int* __restrict__ ei, int E,
                               const int* __restrict__ offs,
                               int* __restrict__ cursor, int* __restrict__ csr_src)
{
    int e = blockIdx.x * 256 + threadIdx.x;
    if (e < E) {
        int s = ei[e];
        int d = ei[E + e];
        int p = offs[d] + atomicAdd(&cursor[d], 1);
        csr_src[p] = s;
    }
}

// ---------------- QKV GEMM via f16x2-split MFMA, XCD-swizzled 1D grid ----------------
// 1500 blocks; 6 blocks sharing an X panel (by x z) are mapped to the SAME XCD so
// the panel is HBM-fetched once and L2-served 5 times. q=187, r=4 chunked bijection.
// z=0 -> Q f32 (ld 256); z=1 -> K f16 in KVh (ld 512, +0); z=2 -> V f16 (ld 512, +256)
template<int K>
__global__ __launch_bounds__(256) void qkv_gemm_mfma(
    const _Float16* __restrict__ Xhi, const _Float16* __restrict__ Xlo,
    const _Float16* __restrict__ WThi, const _Float16* __restrict__ WTlo,
    const float* __restrict__ bq, const float* __restrict__ bk, const float* __restrict__ bv,
    float* __restrict__ Q, _Float16* __restrict__ KVh)
{
    // XCD-bijective decode: hw block i lands on XCD i%8; give each XCD a
    // contiguous chunk of work indices so panel-sharing blocks co-reside.
    int i = blockIdx.x;
    int xcd = i & 7, slot = i >> 3;
    int w = (xcd < 4 ? xcd*188 : 752 + (xcd - 4)*187) + slot;   // 1500 = 4*188+4*187
    int panel = w / 6, sub = w - panel*6;
    int by = sub & 1, z = sub >> 1;
    int bm = panel * 128, bn = by * 128;

    const float* Bb = (z == 0) ? bq : (z == 1) ? bk : bv;
    const _Float16* Whi = WThi + (size_t)z*256*K;
    const _Float16* Wlo = WTlo + (size_t)z*256*K;

    __shared__ _Float16 As_hi[128*32];
    __shared__ _Float16 As_lo[128*32];
    __shared__ _Float16 Bs_hi[128*32];
    __shared__ _Float16 Bs_lo[128*32];

    int tid = threadIdx.x;
    int wv = tid >> 6, l = tid & 63;

    // staging: wave wv covers rows wv*32..wv*32+31 (two 16-row instructions per buffer)
    int srow = wv*32 + (l >> 2);
    size_t gxa = (size_t)(bm + srow)*K + (l & 3)*8;
    size_t gwb = (size_t)(bn + srow)*K + (l & 3)*8;
    int loff = wv*2048 + l*16;   // byte offset in LDS tile

    // compute: wave (wr,wc) sub-tile
    int wr = wv >> 1, wc = wv & 1;
    int fr = l & 15, fk = l >> 4;

    f32x4 acc[4][4] = {};

    for (int k0 = 0; k0 < K; k0 += 32) {
        __syncthreads();   // previous iteration's readers done
        const _Float16* ga = Xhi + gxa + k0;
        const _Float16* gb = Xlo + gxa + k0;
        const _Float16* gc = Whi + gwb + k0;
        const _Float16* gd = Wlo + gwb + k0;
        __builtin_amdgcn_global_load_lds(AS1(ga),            AS3((char*)As_hi + loff),        16, 0, 0);
        __builtin_amdgcn_global_load_lds(AS1(ga + 16*(size_t)K), AS3((char*)As_hi + loff + 1024), 16, 0, 0);
        __builtin_amdgcn_global_load_lds(AS1(gb),            AS3((char*)As_lo + loff),        16, 0, 0);
        __builtin_amdgcn_global_load_lds(AS1(gb + 16*(size_t)K), AS3((char*)As_lo + loff + 1024), 16, 0, 0);
        __builtin_amdgcn_global_load_lds(AS1(gc),            AS3((char*)Bs_hi + loff),        16, 0, 0);
        __builtin_amdgcn_global_load_lds(AS1(gc + 16*(size_t)K), AS3((char*)Bs_hi + loff + 1024), 16, 0, 0);
        __builtin_amdgcn_global_load_lds(AS1(gd),            AS3((char*)Bs_lo + loff),        16, 0, 0);
        __builtin_amdgcn_global_load_lds(AS1(gd + 16*(size_t)K), AS3((char*)Bs_lo + loff + 1024), 16, 0, 0);
        __syncthreads();   // compiler drains vmcnt(0) before this barrier

        f16x8 ah[4], al[4], bh[4], bl[4];
        #pragma unroll
        for (int m = 0; m < 4; m++) {
            int rb = (wr*64 + m*16 + fr)*64 + fk*16;
            ah[m] = *(const f16x8*)((const char*)As_hi + rb);
            al[m] = *(const f16x8*)((const char*)As_lo + rb);
        }
        #pragma unroll
        for (int n = 0; n < 4; n++) {
            int rb = (wc*64 + n*16 + fr)*64 + fk*16;
            bh[n] = *(const f16x8*)((const char*)Bs_hi + rb);
            bl[n] = *(const f16x8*)((const char*)Bs_lo + rb);
        }
        #pragma unroll
        for (int m = 0; m < 4; m++)
            #pragma unroll
            for (int n = 0; n < 4; n++) {
                acc[m][n] = __builtin_amdgcn_mfma_f32_16x16x32_f16(ah[m], bh[n], acc[m][n], 0, 0, 0);
                acc[m][n] = __builtin_amdgcn_mfma_f32_16x16x32_f16(ah[m], bl[n], acc[m][n], 0, 0, 0);
                acc[m][n] = __builtin_amdgcn_mfma_f32_16x16x32_f16(al[m], bh[n], acc[m][n], 0, 0, 0);
            }
    }

    // epilogue: D col=lane&15, row=(lane>>4)*4+reg (m89-verified mapping)
    if (z == 0) {
        #pragma unroll
        for (int n = 0; n < 4; n++) {
            int c = bn + wc*64 + n*16 + fr;
            float bb = Bb[c];
            #pragma unroll
            for (int m = 0; m < 4; m++) {
                int rbase = bm + wr*64 + m*16 + fk*4;
                #pragma unroll
                for (int r = 0; r < 4; r++)
                    Q[(size_t)(rbase + r)*CH + c] = acc[m][n][r] + bb;
            }
        }
    } else {
        _Float16* C = KVh + (z == 1 ? 0 : 256);
        #pragma unroll
        for (int n = 0; n < 4; n++) {
            int c = bn + wc*64 + n*16 + fr;
            float bb = Bb[c];
            #pragma unroll
            for (int m = 0; m < 4; m++) {
                int rbase = bm + wr*64 + m*16 + fk*4;
                #pragma unroll
                for (int r = 0; r < 4; r++)
                    C[(size_t)(rbase + r)*512 + c] = (_Float16)(acc[m][n][r] + bb);
            }
        }
    }
}

// ---------------- edge-softmax aggregation, one wave per node, 2 edges/iter ----------------
// K/V rows are f16 (1 KB/edge); per-XCD KV slice (4 batches ~4.1 MB) ~fits its L2.
__global__ __launch_bounds__(256) void attn_kernel(
    const float* __restrict__ Q, const _Float16* __restrict__ KVh,
    const int* __restrict__ offs, const int* __restrict__ counts,
    const int* __restrict__ csr_src,
    _Float16* __restrict__ X1hi, _Float16* __restrict__ X1lo)
{
    int tid = threadIdx.x;
    int wv = tid >> 6, lane = tid & 63;
    int bid = blockIdx.x;
    int swz = (bid & 7) * (NNODES/4/8) + (bid >> 3);
    int n = swz * 4 + wv;

    float4 qv = *(const float4*)&Q[(size_t)n*CH + lane*4];
    int start = offs[n], deg = counts[n];

    float m = -INFINITY, l = 0.f;
    float4 acc = {0.f, 0.f, 0.f, 0.f};

    int e = 0;
    for (; e + 1 < deg; e += 2) {
        int s0 = csr_src[start + e];
        int s1 = csr_src[start + e + 1];
        const _Float16* kv0 = &KVh[(size_t)s0*512 + lane*4];
        const _Float16* kv1 = &KVh[(size_t)s1*512 + lane*4];
        f16x4 k0h = *(const f16x4*)kv0,      k1h = *(const f16x4*)kv1;
        f16x4 v0h = *(const f16x4*)(kv0+256), v1h = *(const f16x4*)(kv1+256);
        float p0 = (float)k0h[0]*qv.x + (float)k0h[1]*qv.y + (float)k0h[2]*qv.z + (float)k0h[3]*qv.w;
        float p1 = (float)k1h[0]*qv.x + (float)k1h[1]*qv.y + (float)k1h[2]*qv.z + (float)k1h[3]*qv.w;
        p0 += __shfl_xor(p0, 8, 16); p1 += __shfl_xor(p1, 8, 16);
        p0 += __shfl_xor(p0, 4, 16); p1 += __shfl_xor(p1, 4, 16);
        p0 += __shfl_xor(p0, 2, 16); p1 += __shfl_xor(p1, 2, 16);
        p0 += __shfl_xor(p0, 1, 16); p1 += __shfl_xor(p1, 1, 16);
        float sa = p0 * 0.125f, sb = p1 * 0.125f;
        float mn = fmaxf(m, fmaxf(sa, sb));
        float sc = __expf(m - mn);
        float e0 = __expf(sa - mn);
        float e1 = __expf(sb - mn);
        l = l*sc + e0 + e1;
        acc.x = acc.x*sc + e0*(float)v0h[0] + e1*(float)v1h[0];
        acc.y = acc.y*sc + e0*(float)v0h[1] + e1*(float)v1h[1];
        acc.z = acc.z*sc + e0*(float)v0h[2] + e1*(float)v1h[2];
        acc.w = acc.w*sc + e0*(float)v0h[3] + e1*(float)v1h[3];
        m = mn;
    }
    if (e < deg) {
        int s0 = csr_src[start + e];
        const _Float16* kv0 = &KVh[(size_t)s0*512 + lane*4];
        f16x4 k0h = *(const f16x4*)kv0;
        f16x4 v0h = *(const f16x4*)(kv0+256);
        float p0 = (float)k0h[0]*qv.x + (float)k0h[1]*qv.y + (float)k0h[2]*qv.z + (float)k0h[3]*qv.w;
        p0 += __shfl_xor(p0, 8, 16);
        p0 += __shfl_xor(p0, 4, 16);
        p0 += __shfl_xor(p0, 2, 16);
        p0 += __shfl_xor(p0, 1, 16);
        float sa = p0 * 0.125f;
        float mn = fmaxf(m, sa);
        float sc = __expf(m - mn);
        float e0 = __expf(sa - mn);
        l = l*sc + e0;
        acc.x = acc.x*sc + e0*(float)v0h[0];
        acc.y = acc.y*sc + e0*(float)v0h[1];
        acc.z = acc.z*sc + e0*(float)v0h[2];
        acc.w = acc.w*sc + e0*(float)v0h[3];
        m = mn;
    }
    float inv = (l > 0.f) ? 1.f / l : 0.f;
    float o0 = fmaxf(acc.x*inv, 0.f);
    float o1 = fmaxf(acc.y*inv, 0.f);
    float o2 = fmaxf(acc.z*inv, 0.f);
    float o3 = fmaxf(acc.w*inv, 0.f);
    _Float16 h0 = (_Float16)o0, h1 = (_Float16)o1, h2 = (_Float16)o2, h3 = (_Float16)o3;
    f16x4 vh = {h0, h1, h2, h3};
    f16x4 vl = {(_Float16)(o0 - (float)h0), (_Float16)(o1 - (float)h1),
                (_Float16)(o2 - (float)h2), (_Float16)(o3 - (float)h3)};
    *(f16x4*)&X1hi[(size_t)n*CH + lane*4] = vh;
    *(f16x4*)&X1lo[(size_t)n*CH + lane*4] = vl;
}

// ---------------- output head: x = hi + lo reconstruction ----------------
__global__ __launch_bounds__(64) void out_kernel(
    const float* __restrict__ obs,
    const _Float16* __restrict__ X1hi, const _Float16* __restrict__ X1lo,
    const float* __restrict__ ow, const float* __restrict__ ob,
    float* __restrict__ out)
{
    int b = blockIdx.x, lane = threadIdx.x;
    float a = obs[b*OBS_STRIDE + NN*8];
    int agent = (int)fminf(fmaxf(a, 0.f), (float)(NN - 1));
    int g = b*NN + agent;

    float partial[OUTD] = {};
    #pragma unroll
    for (int c = 0; c < 4; c++) {
        int k = c*64 + lane;
        size_t idx = (size_t)g*CH + k;
        float xv = (float)X1hi[idx] + (float)X1lo[idx];
        #pragma unroll
        for (int j = 0; j < OUTD; j++) partial[j] += xv * ow[k*OUTD + j];
    }
    #pragma unroll
    for (int j = 0; j < OUTD; j++) {
        #pragma unroll
        for (int o = 32; o >= 1; o >>= 1) partial[j] += __shfl_xor(partial[j], o, 64);
    }
    if (lane == 0) {
        #pragma unroll
        for (int j = 0; j < OUTD; j++) out[b*OUTD + j] = partial[j] + ob[j];
    }
}

extern "C" void kernel_launch(void* const* d_in, const int* in_sizes, int n_in,
                              void* d_out, int out_size, void* d_ws, size_t ws_size,
                              hipStream_t stream)
{
    const float* obs    = (const float*)d_in[0];
    const int*   ei     = (const int*)d_in[1];
    const int    E      = in_sizes[1] / 2;
    const float* enc_w1 = (const float*)d_in[2];
    const float* enc_b1 = (const float*)d_in[3];
    const float* enc_w2 = (const float*)d_in[4];
    const float* enc_b2 = (const float*)d_in[5];
    const float* c1_wq  = (const float*)d_in[6];
    const float* c1_bq  = (const float*)d_in[7];
    const float* c1_wk  = (const float*)d_in[8];
    const float* c1_bk  = (const float*)d_in[9];
    const float* c1_wv  = (const float*)d_in[10];
    const float* c1_bv  = (const float*)d_in[11];
    const float* c2_wq  = (const float*)d_in[12];
    const float* c2_bq  = (const float*)d_in[13];
    const float* c2_wk  = (const float*)d_in[14];
    const float* c2_bk  = (const float*)d_in[15];
    const float* c2_wv  = (const float*)d_in[16];
    const float* c2_bv  = (const float*)d_in[17];
    const float* out_w  = (const float*)d_in[18];
    const float* out_b  = (const float*)d_in[19];
    float* dout = (float*)d_out;

    // workspace layout (~105 MB)
    float* ws   = (float*)d_ws;
    float* Qb   = ws;                                   // 32000*256 f32
    _Float16* KVh  = (_Float16*)(Qb + (size_t)NNODES*CH);    // 32000*512 f16 (K|V)
    _Float16* X1hi = KVh + (size_t)NNODES*512;               // 32000*256 f16
    _Float16* X1lo = X1hi + (size_t)NNODES*CH;               // 32000*256 f16
    _Float16* h_hi = X1hi;   // alias: encoder output (32000*64) dead before attn1 writes X1hi
    _Float16* h_lo = X1lo;
    _Float16* wt_hi_c1 = X1lo + (size_t)NNODES*CH;      // 3*256*64
    _Float16* wt_lo_c1 = wt_hi_c1 + 3*256*64;
    _Float16* wt_hi_c2 = wt_lo_c1 + 3*256*64;           // 3*256*256
    _Float16* wt_lo_c2 = wt_hi_c2 + 3*256*256;
    int* counts = (int*)(wt_lo_c2 + 3*256*256);
    int* offs   = counts + NNODES;
    int* cursor = offs + NNODES;
    int* csr    = cursor + NNODES;                      // E entries

    hipMemsetAsync(counts, 0, NNODES*sizeof(int), stream);
    hipMemsetAsync(cursor, 0, NNODES*sizeof(int), stream);

    int egrid = (E + 255) / 256;
    count_kernel<<<egrid, 256, 0, stream>>>(ei + E, E, counts);
    scan_kernel<<<1, 1024, 0, stream>>>(counts, offs);
    scatter_kernel<<<egrid, 256, 0, stream>>>(ei, E, offs, cursor, csr);

    split_wt_kernel<<<dim3(256, 1, 6), 64, 0, stream>>>(
        c1_wq, c1_wk, c1_wv, c2_wq, c2_wk, c2_wv,
        wt_hi_c1, wt_lo_c1, wt_hi_c2, wt_lo_c2);

    encoder_kernel<<<NNODES/16, 256, 0, stream>>>(obs, enc_w1, enc_b1, enc_w2, enc_b2, h_hi, h_lo);

    qkv_gemm_mfma<HID><<<1500, 256, 0, stream>>>(h_hi, h_lo, wt_hi_c1, wt_lo_c1,
                                                 c1_bq, c1_bk, c1_bv, Qb, KVh);
    attn_kernel<<<NNODES/4, 256, 0, stream>>>(Qb, KVh, offs, counts, csr, X1hi, X1lo);

    qkv_gemm_mfma<CH><<<1500, 256, 0, stream>>>(X1hi, X1lo, wt_hi_c2, wt_lo_c2,
                                                c2_bq, c2_bk, c2_bv, Qb, KVh);
    attn_kernel<<<NNODES/4, 256, 0, stream>>>(Qb, KVh, offs, counts, csr, X1hi, X1lo);

    out_kernel<<<BSZ, 64, 0, stream>>>(obs, X1hi, X1lo, out_w, out_b, dout);
}

// Round 18
// 318.253 us; speedup vs baseline: 1.8804x; 1.1457x over previous
//
#include <hip/hip_runtime.h>
#include <math.h>

#define BSZ 32
#define NN 1000
#define NNODES (BSZ*NN)
#define D_IN 6
#define HID 64
#define NH 4
#define CH (NH*HID)   /* 256 */
#define OUTD 5
#define OBS_STRIDE (NN*8+1)  /* 8001 */

typedef _Float16 f16x8 __attribute__((ext_vector_type(8)));
typedef _Float16 f16x4 __attribute__((ext_vector_type(4)));
typedef float f32x4 __attribute__((ext_vector_type(4)));

#define AS1(p) ((const __attribute__((address_space(1))) void*)(p))
#define AS3(p) ((__attribute__((address_space(3))) void*)(p))

// ---------------- encoder: feats(6) -> relu(64) -> relu(64), emits f16 hi/lo ----------------
__global__ __launch_bounds__(256) void encoder_kernel(
    const float* __restrict__ obs,
    const float* __restrict__ w1, const float* __restrict__ b1,
    const float* __restrict__ w2, const float* __restrict__ b2,
    _Float16* __restrict__ h_hi, _Float16* __restrict__ h_lo)
{
    __shared__ float W1s[6*64];
    __shared__ float W2s[64*64];
    __shared__ float B1s[64], B2s[64];
    __shared__ float fs[16][6];
    __shared__ float h1s[4][64];

    int tid = threadIdx.x;
    for (int i = tid; i < 6*64; i += 256) W1s[i] = w1[i];
    for (int i = tid; i < 64*64; i += 256) W2s[i] = w2[i];
    if (tid < 64) { B1s[tid] = b1[tid]; B2s[tid] = b2[tid]; }

    int n0 = blockIdx.x * 16;
    if (tid < 96) {
        int node = tid / 6, f = tid % 6;
        int n = n0 + node;
        fs[node][f] = obs[(n/NN)*OBS_STRIDE + (n%NN)*8 + 2 + f];
    }
    int nl = tid >> 6, j = tid & 63;
    __syncthreads();

    #pragma unroll
    for (int p = 0; p < 4; p++) {
        int ln = p*4 + nl;
        float acc = B1s[j];
        #pragma unroll
        for (int i = 0; i < 6; i++) acc += fs[ln][i] * W1s[i*64 + j];
        h1s[nl][j] = fmaxf(acc, 0.f);
        __syncthreads();
        float acc2 = B2s[j];
        #pragma unroll
        for (int i = 0; i < 64; i++) acc2 += h1s[nl][i] * W2s[i*64 + j];
        float v = fmaxf(acc2, 0.f);
        _Float16 hh = (_Float16)v;
        _Float16 hl = (_Float16)(v - (float)hh);
        h_hi[(size_t)(n0 + ln)*64 + j] = hh;
        h_lo[(size_t)(n0 + ln)*64 + j] = hl;
        __syncthreads();
    }
}

// ---------------- weight split+transpose: W[K][256] f32 -> WT[256][K] f16 hi/lo ----------------
__global__ __launch_bounds__(64) void split_wt_kernel(
    const float* __restrict__ w0, const float* __restrict__ w1, const float* __restrict__ w2,
    const float* __restrict__ w3, const float* __restrict__ w4, const float* __restrict__ w5,
    _Float16* __restrict__ hi_c1, _Float16* __restrict__ lo_c1,
    _Float16* __restrict__ hi_c2, _Float16* __restrict__ lo_c2)
{
    int z = blockIdx.z;
    int col = blockIdx.x;
    int t = threadIdx.x;
    const float* W; int Kd; _Float16 *dh, *dl;
    if (z < 3) { W = (z==0 ? w0 : z==1 ? w1 : w2); Kd = 64;
                 dh = hi_c1 + (size_t)z*256*64;  dl = lo_c1 + (size_t)z*256*64; }
    else       { W = (z==3 ? w3 : z==4 ? w4 : w5); Kd = 256;
                 dh = hi_c2 + (size_t)(z-3)*256*256; dl = lo_c2 + (size_t)(z-3)*256*256; }
    for (int k = t; k < Kd; k += 64) {
        float x = W[(size_t)k*256 + col];
        _Float16 h = (_Float16)x;
        dh[(size_t)col*Kd + k] = h;
        dl[(size_t)col*Kd + k] = (_Float16)(x - (float)h);
    }
}

// ---------------- CSR build ----------------
__global__ void count_kernel(const int* __restrict__ dst, int E, int* __restrict__ counts)
{
    int e = blockIdx.x * 256 + threadIdx.x;
    if (e < E) atomicAdd(&counts[dst[e]], 1);
}

// hierarchical scan: 125 blocks x 256 -> block-local exclusive + block totals
__global__ __launch_bounds__(256) void scan_local_kernel(
    const int* __restrict__ counts, int* __restrict__ offs, int* __restrict__ btot)
{
    __shared__ int ps[256];
    int t = threadIdx.x;
    int gid = blockIdx.x*256 + t;
    int c = counts[gid];
    ps[t] = c;
    __syncthreads();
    #pragma unroll
    for (int o = 1; o < 256; o <<= 1) {
        int v = (t >= o) ? ps[t - o] : 0;
        __syncthreads();
        ps[t] += v;
        __syncthreads();
    }
    offs[gid] = ps[t] - c;              // exclusive within block
    if (t == 255) btot[blockIdx.x] = ps[255];
}

// scan the 125 block totals (exclusive)
__global__ __launch_bounds__(128) void scan_tot_kernel(
    const int* __restrict__ btot, int* __restrict__ bbase)
{
    __shared__ int ps[128];
    int t = threadIdx.x;
    int v = (t < 125) ? btot[t] : 0;
    ps[t] = v;
    __syncthreads();
    #pragma unroll
    for (int o = 1; o < 128; o <<= 1) {
        int x = (t >= o) ? ps[t - o] : 0;
        __syncthreads();
        ps[t] += x;
        __syncthreads();
    }
    if (t < 125) bbase[t] = ps[t] - v;
}

// add block bases in place
__global__ __launch_bounds__(256) void scan_add_kernel(
    int* __restrict__ offs, const int* __restrict__ bbase)
{
    int gid = blockIdx.x*256 + threadIdx.x;
    offs[gid] += bbase[blockIdx.x];
}

__global__ void scatter_kernel(const int* __restrict__ ei, int E,
                               const int* __restrict__ offs,
                               int* __restrict__ cursor, int* __restrict__ csr_src)
{
    int e = blockIdx.x * 256 + threadIdx.x;
    if (e < E) {
        int s = ei[e];
        int d = ei[E + e];
        int p = offs[d] + atomicAdd(&cursor[d], 1);
        csr_src[p] = s;
    }
}

// ---------------- QKV GEMM via f16x2-split MFMA, XCD-swizzled 1D grid ----------------
// 1500 blocks; 6 blocks sharing an X panel (by x z) are mapped to the SAME XCD so
// the panel is HBM-fetched once and L2-served 5 times. q=187, r=4 chunked bijection.
// z=0 -> Q f32 (ld 256); z=1 -> K f16 in KVh (ld 512, +0); z=2 -> V f16 (ld 512, +256)
template<int K>
__global__ __launch_bounds__(256) void qkv_gemm_mfma(
    const _Float16* __restrict__ Xhi, const _Float16* __restrict__ Xlo,
    const _Float16* __restrict__ WThi, const _Float16* __restrict__ WTlo,
    const float* __restrict__ bq, const float* __restrict__ bk, const float* __restrict__ bv,
    float* __restrict__ Q, _Float16* __restrict__ KVh)
{
    // XCD-bijective decode: hw block i lands on XCD i%8; give each XCD a
    // contiguous chunk of work indices so panel-sharing blocks co-reside.
    int i = blockIdx.x;
    int xcd = i & 7, slot = i >> 3;
    int w = (xcd < 4 ? xcd*188 : 752 + (xcd - 4)*187) + slot;   // 1500 = 4*188+4*187
    int panel = w / 6, sub = w - panel*6;
    int by = sub & 1, z = sub >> 1;
    int bm = panel * 128, bn = by * 128;

    const float* Bb = (z == 0) ? bq : (z == 1) ? bk : bv;
    const _Float16* Whi = WThi + (size_t)z*256*K;
    const _Float16* Wlo = WTlo + (size_t)z*256*K;

    __shared__ _Float16 As_hi[128*32];
    __shared__ _Float16 As_lo[128*32];
    __shared__ _Float16 Bs_hi[128*32];
    __shared__ _Float16 Bs_lo[128*32];

    int tid = threadIdx.x;
    int wv = tid >> 6, l = tid & 63;

    // staging: wave wv covers rows wv*32..wv*32+31 (two 16-row instructions per buffer)
    int srow = wv*32 + (l >> 2);
    size_t gxa = (size_t)(bm + srow)*K + (l & 3)*8;
    size_t gwb = (size_t)(bn + srow)*K + (l & 3)*8;
    int loff = wv*2048 + l*16;   // byte offset in LDS tile

    // compute: wave (wr,wc) sub-tile
    int wr = wv >> 1, wc = wv & 1;
    int fr = l & 15, fk = l >> 4;

    f32x4 acc[4][4] = {};

    for (int k0 = 0; k0 < K; k0 += 32) {
        __syncthreads();   // previous iteration's readers done
        const _Float16* ga = Xhi + gxa + k0;
        const _Float16* gb = Xlo + gxa + k0;
        const _Float16* gc = Whi + gwb + k0;
        const _Float16* gd = Wlo + gwb + k0;
        __builtin_amdgcn_global_load_lds(AS1(ga),            AS3((char*)As_hi + loff),        16, 0, 0);
        __builtin_amdgcn_global_load_lds(AS1(ga + 16*(size_t)K), AS3((char*)As_hi + loff + 1024), 16, 0, 0);
        __builtin_amdgcn_global_load_lds(AS1(gb),            AS3((char*)As_lo + loff),        16, 0, 0);
        __builtin_amdgcn_global_load_lds(AS1(gb + 16*(size_t)K), AS3((char*)As_lo + loff + 1024), 16, 0, 0);
        __builtin_amdgcn_global_load_lds(AS1(gc),            AS3((char*)Bs_hi + loff),        16, 0, 0);
        __builtin_amdgcn_global_load_lds(AS1(gc + 16*(size_t)K), AS3((char*)Bs_hi + loff + 1024), 16, 0, 0);
        __builtin_amdgcn_global_load_lds(AS1(gd),            AS3((char*)Bs_lo + loff),        16, 0, 0);
        __builtin_amdgcn_global_load_lds(AS1(gd + 16*(size_t)K), AS3((char*)Bs_lo + loff + 1024), 16, 0, 0);
        __syncthreads();   // compiler drains vmcnt(0) before this barrier

        f16x8 ah[4], al[4], bh[4], bl[4];
        #pragma unroll
        for (int m = 0; m < 4; m++) {
            int rb = (wr*64 + m*16 + fr)*64 + fk*16;
            ah[m] = *(const f16x8*)((const char*)As_hi + rb);
            al[m] = *(const f16x8*)((const char*)As_lo + rb);
        }
        #pragma unroll
        for (int n = 0; n < 4; n++) {
            int rb = (wc*64 + n*16 + fr)*64 + fk*16;
            bh[n] = *(const f16x8*)((const char*)Bs_hi + rb);
            bl[n] = *(const f16x8*)((const char*)Bs_lo + rb);
        }
        #pragma unroll
        for (int m = 0; m < 4; m++)
            #pragma unroll
            for (int n = 0; n < 4; n++) {
                acc[m][n] = __builtin_amdgcn_mfma_f32_16x16x32_f16(ah[m], bh[n], acc[m][n], 0, 0, 0);
                acc[m][n] = __builtin_amdgcn_mfma_f32_16x16x32_f16(ah[m], bl[n], acc[m][n], 0, 0, 0);
                acc[m][n] = __builtin_amdgcn_mfma_f32_16x16x32_f16(al[m], bh[n], acc[m][n], 0, 0, 0);
            }
    }

    // epilogue: D col=lane&15, row=(lane>>4)*4+reg (m89-verified mapping)
    if (z == 0) {
        #pragma unroll
        for (int n = 0; n < 4; n++) {
            int c = bn + wc*64 + n*16 + fr;
            float bb = Bb[c];
            #pragma unroll
            for (int m = 0; m < 4; m++) {
                int rbase = bm + wr*64 + m*16 + fk*4;
                #pragma unroll
                for (int r = 0; r < 4; r++)
                    Q[(size_t)(rbase + r)*CH + c] = acc[m][n][r] + bb;
            }
        }
    } else {
        _Float16* C = KVh + (z == 1 ? 0 : 256);
        #pragma unroll
        for (int n = 0; n < 4; n++) {
            int c = bn + wc*64 + n*16 + fr;
            float bb = Bb[c];
            #pragma unroll
            for (int m = 0; m < 4; m++) {
                int rbase = bm + wr*64 + m*16 + fk*4;
                #pragma unroll
                for (int r = 0; r < 4; r++)
                    C[(size_t)(rbase + r)*512 + c] = (_Float16)(acc[m][n][r] + bb);
            }
        }
    }
}

// ---------------- edge-softmax aggregation, one wave per node, 2 edges/iter ----------------
// K/V rows are f16 (1 KB/edge); per-XCD KV slice (4 batches ~4.1 MB) ~fits its L2.
__global__ __launch_bounds__(256) void attn_kernel(
    const float* __restrict__ Q, const _Float16* __restrict__ KVh,
    const int* __restrict__ offs, const int* __restrict__ counts,
    const int* __restrict__ csr_src,
    _Float16* __restrict__ X1hi, _Float16* __restrict__ X1lo)
{
    int tid = threadIdx.x;
    int wv = tid >> 6, lane = tid & 63;
    int bid = blockIdx.x;
    int swz = (bid & 7) * (NNODES/4/8) + (bid >> 3);
    int n = swz * 4 + wv;

    float4 qv = *(const float4*)&Q[(size_t)n*CH + lane*4];
    int start = offs[n], deg = counts[n];

    float m = -INFINITY, l = 0.f;
    float4 acc = {0.f, 0.f, 0.f, 0.f};

    int e = 0;
    for (; e + 1 < deg; e += 2) {
        int s0 = csr_src[start + e];
        int s1 = csr_src[start + e + 1];
        const _Float16* kv0 = &KVh[(size_t)s0*512 + lane*4];
        const _Float16* kv1 = &KVh[(size_t)s1*512 + lane*4];
        f16x4 k0h = *(const f16x4*)kv0,      k1h = *(const f16x4*)kv1;
        f16x4 v0h = *(const f16x4*)(kv0+256), v1h = *(const f16x4*)(kv1+256);
        float p0 = (float)k0h[0]*qv.x + (float)k0h[1]*qv.y + (float)k0h[2]*qv.z + (float)k0h[3]*qv.w;
        float p1 = (float)k1h[0]*qv.x + (float)k1h[1]*qv.y + (float)k1h[2]*qv.z + (float)k1h[3]*qv.w;
        p0 += __shfl_xor(p0, 8, 16); p1 += __shfl_xor(p1, 8, 16);
        p0 += __shfl_xor(p0, 4, 16); p1 += __shfl_xor(p1, 4, 16);
        p0 += __shfl_xor(p0, 2, 16); p1 += __shfl_xor(p1, 2, 16);
        p0 += __shfl_xor(p0, 1, 16); p1 += __shfl_xor(p1, 1, 16);
        float sa = p0 * 0.125f, sb = p1 * 0.125f;
        float mn = fmaxf(m, fmaxf(sa, sb));
        float sc = __expf(m - mn);
        float e0 = __expf(sa - mn);
        float e1 = __expf(sb - mn);
        l = l*sc + e0 + e1;
        acc.x = acc.x*sc + e0*(float)v0h[0] + e1*(float)v1h[0];
        acc.y = acc.y*sc + e0*(float)v0h[1] + e1*(float)v1h[1];
        acc.z = acc.z*sc + e0*(float)v0h[2] + e1*(float)v1h[2];
        acc.w = acc.w*sc + e0*(float)v0h[3] + e1*(float)v1h[3];
        m = mn;
    }
    if (e < deg) {
        int s0 = csr_src[start + e];
        const _Float16* kv0 = &KVh[(size_t)s0*512 + lane*4];
        f16x4 k0h = *(const f16x4*)kv0;
        f16x4 v0h = *(const f16x4*)(kv0+256);
        float p0 = (float)k0h[0]*qv.x + (float)k0h[1]*qv.y + (float)k0h[2]*qv.z + (float)k0h[3]*qv.w;
        p0 += __shfl_xor(p0, 8, 16);
        p0 += __shfl_xor(p0, 4, 16);
        p0 += __shfl_xor(p0, 2, 16);
        p0 += __shfl_xor(p0, 1, 16);
        float sa = p0 * 0.125f;
        float mn = fmaxf(m, sa);
        float sc = __expf(m - mn);
        float e0 = __expf(sa - mn);
        l = l*sc + e0;
        acc.x = acc.x*sc + e0*(float)v0h[0];
        acc.y = acc.y*sc + e0*(float)v0h[1];
        acc.z = acc.z*sc + e0*(float)v0h[2];
        acc.w = acc.w*sc + e0*(float)v0h[3];
        m = mn;
    }
    float inv = (l > 0.f) ? 1.f / l : 0.f;
    float o0 = fmaxf(acc.x*inv, 0.f);
    float o1 = fmaxf(acc.y*inv, 0.f);
    float o2 = fmaxf(acc.z*inv, 0.f);
    float o3 = fmaxf(acc.w*inv, 0.f);
    _Float16 h0 = (_Float16)o0, h1 = (_Float16)o1, h2 = (_Float16)o2, h3 = (_Float16)o3;
    f16x4 vh = {h0, h1, h2, h3};
    f16x4 vl = {(_Float16)(o0 - (float)h0), (_Float16)(o1 - (float)h1),
                (_Float16)(o2 - (float)h2), (_Float16)(o3 - (float)h3)};
    *(f16x4*)&X1hi[(size_t)n*CH + lane*4] = vh;
    *(f16x4*)&X1lo[(size_t)n*CH + lane*4] = vl;
}

// ---------------- output head: x = hi + lo reconstruction ----------------
__global__ __launch_bounds__(64) void out_kernel(
    const float* __restrict__ obs,
    const _Float16* __restrict__ X1hi, const _Float16* __restrict__ X1lo,
    const float* __restrict__ ow, const float* __restrict__ ob,
    float* __restrict__ out)
{
    int b = blockIdx.x, lane = threadIdx.x;
    float a = obs[b*OBS_STRIDE + NN*8];
    int agent = (int)fminf(fmaxf(a, 0.f), (float)(NN - 1));
    int g = b*NN + agent;

    float partial[OUTD] = {};
    #pragma unroll
    for (int c = 0; c < 4; c++) {
        int k = c*64 + lane;
        size_t idx = (size_t)g*CH + k;
        float xv = (float)X1hi[idx] + (float)X1lo[idx];
        #pragma unroll
        for (int j = 0; j < OUTD; j++) partial[j] += xv * ow[k*OUTD + j];
    }
    #pragma unroll
    for (int j = 0; j < OUTD; j++) {
        #pragma unroll
        for (int o = 32; o >= 1; o >>= 1) partial[j] += __shfl_xor(partial[j], o, 64);
    }
    if (lane == 0) {
        #pragma unroll
        for (int j = 0; j < OUTD; j++) out[b*OUTD + j] = partial[j] + ob[j];
    }
}

extern "C" void kernel_launch(void* const* d_in, const int* in_sizes, int n_in,
                              void* d_out, int out_size, void* d_ws, size_t ws_size,
                              hipStream_t stream)
{
    const float* obs    = (const float*)d_in[0];
    const int*   ei     = (const int*)d_in[1];
    const int    E      = in_sizes[1] / 2;
    const float* enc_w1 = (const float*)d_in[2];
    const float* enc_b1 = (const float*)d_in[3];
    const float* enc_w2 = (const float*)d_in[4];
    const float* enc_b2 = (const float*)d_in[5];
    const float* c1_wq  = (const float*)d_in[6];
    const float* c1_bq  = (const float*)d_in[7];
    const float* c1_wk  = (const float*)d_in[8];
    const float* c1_bk  = (const float*)d_in[9];
    const float* c1_wv  = (const float*)d_in[10];
    const float* c1_bv  = (const float*)d_in[11];
    const float* c2_wq  = (const float*)d_in[12];
    const float* c2_bq  = (const float*)d_in[13];
    const float* c2_wk  = (const float*)d_in[14];
    const float* c2_bk  = (const float*)d_in[15];
    const float* c2_wv  = (const float*)d_in[16];
    const float* c2_bv  = (const float*)d_in[17];
    const float* out_w  = (const float*)d_in[18];
    const float* out_b  = (const float*)d_in[19];
    float* dout = (float*)d_out;

    // workspace layout (~105 MB)
    float* ws   = (float*)d_ws;
    float* Qb   = ws;                                   // 32000*256 f32
    _Float16* KVh  = (_Float16*)(Qb + (size_t)NNODES*CH);    // 32000*512 f16 (K|V)
    _Float16* X1hi = KVh + (size_t)NNODES*512;               // 32000*256 f16
    _Float16* X1lo = X1hi + (size_t)NNODES*CH;               // 32000*256 f16
    _Float16* h_hi = X1hi;   // alias: encoder output (32000*64) dead before attn1 writes X1hi
    _Float16* h_lo = X1lo;
    _Float16* wt_hi_c1 = X1lo + (size_t)NNODES*CH;      // 3*256*64
    _Float16* wt_lo_c1 = wt_hi_c1 + 3*256*64;
    _Float16* wt_hi_c2 = wt_lo_c1 + 3*256*64;           // 3*256*256
    _Float16* wt_lo_c2 = wt_hi_c2 + 3*256*256;
    int* counts = (int*)(wt_lo_c2 + 3*256*256);
    int* offs   = counts + NNODES;
    int* cursor = offs + NNODES;
    int* btot   = cursor + NNODES;                      // 125 (+pad)
    int* bbase  = btot + 128;
    int* csr    = bbase + 128;                          // E entries

    hipMemsetAsync(counts, 0, NNODES*sizeof(int), stream);
    hipMemsetAsync(cursor, 0, NNODES*sizeof(int), stream);

    int egrid = (E + 255) / 256;
    count_kernel<<<egrid, 256, 0, stream>>>(ei + E, E, counts);
    scan_local_kernel<<<NNODES/256, 256, 0, stream>>>(counts, offs, btot);
    scan_tot_kernel<<<1, 128, 0, stream>>>(btot, bbase);
    scan_add_kernel<<<NNODES/256, 256, 0, stream>>>(offs, bbase);
    scatter_kernel<<<egrid, 256, 0, stream>>>(ei, E, offs, cursor, csr);

    split_wt_kernel<<<dim3(256, 1, 6), 64, 0, stream>>>(
        c1_wq, c1_wk, c1_wv, c2_wq, c2_wk, c2_wv,
        wt_hi_c1, wt_lo_c1, wt_hi_c2, wt_lo_c2);

    encoder_kernel<<<NNODES/16, 256, 0, stream>>>(obs, enc_w1, enc_b1, enc_w2, enc_b2, h_hi, h_lo);

    qkv_gemm_mfma<HID><<<1500, 256, 0, stream>>>(h_hi, h_lo, wt_hi_c1, wt_lo_c1,
                                                 c1_bq, c1_bk, c1_bv, Qb, KVh);
    attn_kernel<<<NNODES/4, 256, 0, stream>>>(Qb, KVh, offs, counts, csr, X1hi, X1lo);

    qkv_gemm_mfma<CH><<<1500, 256, 0, stream>>>(X1hi, X1lo, wt_hi_c2, wt_lo_c2,
                                                c2_bq, c2_bk, c2_bv, Qb, KVh);
    attn_kernel<<<NNODES/4, 256, 0, stream>>>(Qb, KVh, offs, counts, csr, X1hi, X1lo);

    out_kernel<<<BSZ, 64, 0, stream>>>(obs, X1hi, X1lo, out_w, out_b, dout);
}